// Round 8
// baseline (288.073 us; speedup 1.0000x reference)
//
#include <hip/hip_runtime.h>
#include <hip/hip_bf16.h>
#include <hip/hip_fp16.h>

#define NN 100000
#define NE 1600000
#define FI 80
#define HD 64
#define NBLK 391  // ceil(NN/256)

typedef _Float16 f16x8 __attribute__((ext_vector_type(8)));
typedef float f32x4 __attribute__((ext_vector_type(4)));

// ---------------- fused weight precompute ----------------
// Wc_t[j][k] (fp16, [128][96], k>=80 zero): j<64: (Wz@lzW[0:64])[k][j]; j>=64: (Wh@lhW[0:64])[k][j-64]
// W1_t[j][k] (fp16, [128][64]): j<64: W1[k][j]; j>=64: W1[64+k][j-64]  (mlp_W1 is (128,64), stride 64)
// bzp/bhp = fused gate biases (f32).  (H=0 => R-gate dead; softmax(1)=1 => attention dead)
__global__ void fuse_weights(const float* __restrict__ Wz, const float* __restrict__ bz,
                             const float* __restrict__ lzW, const float* __restrict__ lzb,
                             const float* __restrict__ Wh, const float* __restrict__ bh,
                             const float* __restrict__ lhW, const float* __restrict__ lhb,
                             const float* __restrict__ W1,
                             _Float16* __restrict__ Wct, _Float16* __restrict__ W1t,
                             float* __restrict__ bzp, float* __restrict__ bhp) {
    int j = blockIdx.x;      // 0..127 output col
    int k = threadIdx.x;     // 0..127
    if (blockIdx.y == 1) {
        if (k < HD) {
            float v = (j < HD) ? W1[k * HD + j] : W1[(HD + k) * HD + (j - HD)];
            W1t[j * HD + k] = (_Float16)v;
        }
        return;
    }
    bool isZ = j < 64;
    int jj = isZ ? j : j - 64;
    const float* W = isZ ? Wz : Wh;
    const float* L = isZ ? lzW : lhW;
    if (k < FI) {
        float acc = 0.f;
        for (int i = 0; i < HD; ++i) acc = fmaf(W[k * HD + i], L[i * HD + jj], acc);
        Wct[j * 96 + k] = (_Float16)acc;
    } else if (k < 96) {
        Wct[j * 96 + k] = (_Float16)0.f;
    } else if (k == 96) {
        const float* bb = isZ ? bz : bh;
        const float* lb = isZ ? lzb : lhb;
        float acc = lb[jj];
        for (int i = 0; i < HD; ++i) acc = fmaf(bb[i], L[i * HD + jj], acc);
        (isZ ? bzp : bhp)[jj] = acc;
    }
}

// ---------------- degree+count+rank in ONE u32 atomic + DIRECT capped-CSR fill ----------------
// degcnt bits[26:31]=count (cnt<=63: Poisson(16) tail P~1e-14), bits[0:25]=sum(ew) 2^-20 fixed
// (63*2^20 < 2^26, no carry). Returned old>>26 = rank -> slot d*64+rank, NO scan/second pass.
__global__ void degcnt_init(unsigned* degcnt) {
    int i = blockIdx.x * 256 + threadIdx.x;
    if (i < NN) degcnt[i] = 0u;
}

__global__ void deg_scatter_fill(const int* __restrict__ gsrc, const int* __restrict__ gdst,
                                 const float* __restrict__ ew,
                                 unsigned* degcnt, unsigned* __restrict__ csr) {
    int e = blockIdx.x * 256 + threadIdx.x;
    if (e >= NE) return;
    int s = gsrc[e], d = gdst[e];
    float w = ew[e];
    unsigned val = (1u << 26) | (unsigned)(w * 1048576.0f + 0.5f);
    unsigned old = atomicAdd(&degcnt[d], val);
    unsigned r = old >> 26;
    if (r < 64u) {                                      // guard vs astronomically-unlikely overflow
        unsigned q = (unsigned)(w * 32767.0f + 0.5f);   // ew in [0,1) -> <= 32767
        csr[((unsigned)d << 6) | r] = ((unsigned)s << 15) | q;
    }
}

// ---------------- y table (y[n]=dinv[n]*x[n], fp16, 96-half rows) + fused decode ----------------
__global__ void build_y(const float* __restrict__ x, const unsigned* __restrict__ degcnt,
                        ushort* __restrict__ yh, float* __restrict__ dinv, int* __restrict__ cnt) {
    int i = blockIdx.x * 256 + threadIdx.x;   // over NN*48 half2
    if (i >= NN * 48) return;
    int n = i / 48, p = i % 48;
    unsigned v = degcnt[n];
    float deg = 1.0f + (float)(v & 0x03FFFFFFu) * (1.0f / 1048576.0f);
    float di = rsqrtf(deg);
    if (p == 0) { dinv[n] = di; cnt[n] = (int)(v >> 26); }
    __half2 h;
    if (p < 40) {
        float2 vv = *(const float2*)(x + (size_t)n * FI + 2 * p);
        h = __floats2half2_rn(di * vv.x, di * vv.y);
    } else {
        h = __floats2half2_rn(0.f, 0.f);
    }
    *(__half2*)(yh + (size_t)n * 96 + 2 * p) = h;
}

// ---------------- gather aggregation ----------------
// acc = y[n] + sum ew*y[src];  agg[n] = dinv[n]*acc  (fp16 out); capped-CSR row = [n*64, n*64+cnt)
__global__ __launch_bounds__(256) void gather_agg(const int* __restrict__ cnt,
                                                  const unsigned* __restrict__ csr,
                                                  const float* __restrict__ dinv,
                                                  const ushort* __restrict__ yh,
                                                  ushort* __restrict__ aggh) {
    int t = blockIdx.x * 256 + threadIdx.x;
    int n = t >> 3, k = t & 7;
    if (n >= NN) return;
    float di = dinv[n];
    const ushort* yn = yh + (size_t)n * 96;
    float2 acc[5];
#pragma unroll
    for (int j = 0; j < 5; ++j)
        acc[j] = __half22float2(*(const __half2*)(yn + 2 * k + 16 * j));
    int beg = n << 6, end = beg + cnt[n];
    for (int i = beg; i < end; ++i) {
        unsigned ent = csr[i];                 // lane-uniform within 8-lane group
        float c = (float)(ent & 0x7FFFu) * (1.0f / 32767.0f);
        const ushort* ys = yh + (size_t)(ent >> 15) * 96;
#pragma unroll
        for (int j = 0; j < 5; ++j) {
            float2 v = __half22float2(*(const __half2*)(ys + 2 * k + 16 * j));
            acc[j].x = fmaf(c, v.x, acc[j].x);
            acc[j].y = fmaf(c, v.y, acc[j].y);
        }
    }
    ushort* an = aggh + (size_t)n * FI;
#pragma unroll
    for (int j = 0; j < 5; ++j)
        *(__half2*)(an + 2 * k + 16 * j) = __floats2half2_rn(di * acc[j].x, di * acc[j].y);
}

// ---------------- node kernel: MFMA fp16 two-stage GEMM ----------------
// GEMM1: u(16x80,fp16) @ Wc(80x128) -> gates -> h(16x64);  GEMM2: h @ W1(64x128) -> ab fp16
// C-layout: col=lane&15, row=(lane>>4)*4+r (m89-verified); k-perm consistent on A/B sides.
__global__ __launch_bounds__(256) void node_kernel(const ushort* __restrict__ aggh,
        const _Float16* __restrict__ Wct, const _Float16* __restrict__ W1t,
        const float* __restrict__ bzp, const float* __restrict__ bhp,
        const float* __restrict__ b1, ushort* __restrict__ abh) {
    __shared__ __align__(16) _Float16 sWc[128 * 104];   // stride 104 halves: 16B-aligned rows
    __shared__ __align__(16) _Float16 sW1[128 * 72];    // stride 72
    __shared__ __align__(16) _Float16 wbuf[4][2176];    // per-wave: h (stride 72) / out (stride 136)
    int tid = threadIdx.x;
    for (int i = tid; i < 1536; i += 256) {
        int col = i / 12, ko = (i % 12) * 8;
        *(uint4*)&sWc[col * 104 + ko] = ((const uint4*)Wct)[i];
    }
    for (int i = tid; i < 1024; i += 256) {
        int col = i / 8, ko = (i % 8) * 8;
        *(uint4*)&sW1[col * 72 + ko] = ((const uint4*)W1t)[i];
    }
    __syncthreads();

    int lane = tid & 63, wv = tid >> 6;
    int q = lane & 15, kg = lane >> 4;
    _Float16* hwb = wbuf[wv];

    float bzc[4], bhc[4], b1c[4];
#pragma unroll
    for (int t = 0; t < 4; ++t) {
        bzc[t] = bzp[q + 16 * t];
        bhc[t] = bhp[q + 16 * t];
        b1c[t] = b1[q + 16 * t];
    }

    const int NT = (NN + 63) >> 6;
    for (int tile = blockIdx.x; tile < NT; tile += gridDim.x) {
        int m0 = tile * 64 + wv * 16;
        int node = m0 + q;
        bool rv = node < NN;
        const _Float16* up = (const _Float16*)(aggh + (size_t)node * FI);
        f16x8 a1[3];
#pragma unroll
        for (int ks = 0; ks < 3; ++ks) {
            int kk = ks * 32 + kg * 8;
            a1[ks] = (rv && kk < FI) ? *(const f16x8*)(up + kk) : f16x8{};
        }
        f32x4 acc[8];
#pragma unroll
        for (int t = 0; t < 8; ++t) {
            const _Float16* wp = &sWc[(q + 16 * t) * 104 + kg * 8];
            f32x4 a = {0.f, 0.f, 0.f, 0.f};
            a = __builtin_amdgcn_mfma_f32_16x16x32_f16(a1[0], *(const f16x8*)(wp), a, 0, 0, 0);
            a = __builtin_amdgcn_mfma_f32_16x16x32_f16(a1[1], *(const f16x8*)(wp + 32), a, 0, 0, 0);
            a = __builtin_amdgcn_mfma_f32_16x16x32_f16(a1[2], *(const f16x8*)(wp + 64), a, 0, 0, 0);
            acc[t] = a;
        }
        // gates: cols 0..63 = Z-pre (acc[0..3]), 64..127 = H-pre (acc[4..7])
#pragma unroll
        for (int t = 0; t < 4; ++t) {
#pragma unroll
            for (int r = 0; r < 4; ++r) {
                float z = acc[t][r] + bzc[t];
                float p = acc[t + 4][r] + bhc[t];
                float Z = 1.f / (1.f + __expf(-z));
                float p2 = fminf(fmaxf(2.f * p, -60.f), 60.f);
                float e2 = __expf(p2);
                float Ht = (e2 - 1.f) / (e2 + 1.f);
                hwb[(kg * 4 + r) * 72 + q + 16 * t] = (_Float16)((1.f - Z) * Ht);
            }
        }
        f16x8 a2[2];
        a2[0] = *(const f16x8*)&hwb[q * 72 + kg * 8];
        a2[1] = *(const f16x8*)&hwb[q * 72 + 32 + kg * 8];
#pragma unroll
        for (int t = 0; t < 8; ++t) {
            const _Float16* wp = &sW1[(q + 16 * t) * 72 + kg * 8];
            f32x4 a = {0.f, 0.f, 0.f, 0.f};
            a = __builtin_amdgcn_mfma_f32_16x16x32_f16(a2[0], *(const f16x8*)(wp), a, 0, 0, 0);
            a = __builtin_amdgcn_mfma_f32_16x16x32_f16(a2[1], *(const f16x8*)(wp + 32), a, 0, 0, 0);
            float bb = (t < 4) ? b1c[t] : 0.f;   // b-part (cols 64..127) has no bias
#pragma unroll
            for (int r = 0; r < 4; ++r)
                hwb[(kg * 4 + r) * 136 + q + 16 * t] = (_Float16)(a[r] + bb);
        }
        // coalesced copy-out: 16 nodes x 128 halves
#pragma unroll
        for (int i = lane; i < 256; i += 64) {
            int nd = i >> 4, off = (i & 15) * 8;
            int n2 = m0 + nd;
            if (n2 < NN)
                *(uint4*)(abh + (size_t)n2 * 128 + off) = *(const uint4*)&hwb[nd * 136 + off];
        }
    }
}

// ---------------- edge classifier: 8 lanes/edge, fp16 gathers ----------------
__global__ __launch_bounds__(256) void edge_kernel(const ushort* __restrict__ abh,
                                                   const int* __restrict__ esrc, const int* __restrict__ edst,
                                                   const float* __restrict__ W2, const float* __restrict__ b2,
                                                   float* __restrict__ out) {
    int t = blockIdx.x * 256 + threadIdx.x;
    int e = t >> 3, q = t & 7;
    if (e >= NE) return;
    int s = esrc[e], d = edst[e];
    uint4 a4 = *(const uint4*)(abh + (size_t)s * 128 + q * 8);
    uint4 b4 = *(const uint4*)(abh + (size_t)d * 128 + 64 + q * 8);
    const __half2* ah = (const __half2*)&a4;
    const __half2* bh2 = (const __half2*)&b4;
    const float4* wv = (const float4*)(W2 + q * 16);
    float o0 = 0.f, o1 = 0.f;
#pragma unroll
    for (int j = 0; j < 4; ++j) {
        float2 av = __half22float2(ah[j]);
        float2 bv = __half22float2(bh2[j]);
        float h0 = fmaxf(av.x + bv.x, 0.f);
        float h1 = fmaxf(av.y + bv.y, 0.f);
        float4 w = wv[j];
        o0 = fmaf(h0, w.x, fmaf(h1, w.z, o0));
        o1 = fmaf(h0, w.y, fmaf(h1, w.w, o1));
    }
    o0 += __shfl_xor(o0, 4, 8); o0 += __shfl_xor(o0, 2, 8); o0 += __shfl_xor(o0, 1, 8);
    o1 += __shfl_xor(o1, 4, 8); o1 += __shfl_xor(o1, 2, 8); o1 += __shfl_xor(o1, 1, 8);
    if (q == 0) {
        float2 r;
        r.x = o0 + b2[0];
        r.y = o1 + b2[1];
        *(float2*)(out + (size_t)e * 2) = r;
    }
}

extern "C" void kernel_launch(void* const* d_in, const int* in_sizes, int n_in,
                              void* d_out, int out_size, void* d_ws, size_t ws_size,
                              hipStream_t stream) {
    (void)in_sizes; (void)n_in; (void)out_size; (void)ws_size;
    const float* x    = (const float*)d_in[0];
    const int*   ei   = (const int*)d_in[1];
    const float* ew   = (const float*)d_in[2];
    const int*   esrc = (const int*)d_in[3];
    const int*   edst = (const int*)d_in[4];
    const float* Wz   = (const float*)d_in[6];
    const float* bz   = (const float*)d_in[7];
    const float* lzW  = (const float*)d_in[8];
    const float* lzb  = (const float*)d_in[9];
    const float* Wh   = (const float*)d_in[14];
    const float* bh   = (const float*)d_in[15];
    const float* lhW  = (const float*)d_in[16];
    const float* lhb  = (const float*)d_in[17];
    const float* W1   = (const float*)d_in[18];
    const float* b1   = (const float*)d_in[19];
    const float* W2   = (const float*)d_in[20];
    const float* b2   = (const float*)d_in[21];
    float* out = (float*)d_out;

    float* ws = (float*)d_ws;
    float* bzp = ws;                                     // 64
    float* bhp = ws + 64;                                // 64
    _Float16* Wct = (_Float16*)(ws + 128);               // 12288 halves
    _Float16* W1t = (_Float16*)(ws + 6272);              // 8192 halves
    unsigned* degcnt = (unsigned*)(ws + 10368);          // 100K u32
    float* dinv     = ws + 110368;                       // 100K f32
    int*   cnt      = (int*)(ws + 210368);               // 100K i32
    ushort* yh   = (ushort*)(ws + 310368);               // 9.6M halves (100K x 96), 16B aligned
    ushort* aggh = (ushort*)(ws + 5110368);              // 8M halves (100K x 80), 16B aligned
    unsigned* csr = (unsigned*)(ws + 9110368);           // 6.4M u32 capped-CSR (live: scatter..gather)
    ushort* abh = (ushort*)(ws + 9110368);               // 12.8M halves (live: node..edge), aliases csr

    const int* g_src = ei;
    const int* g_dst = ei + NE;

    fuse_weights<<<dim3(128, 2), 128, 0, stream>>>(Wz, bz, lzW, lzb, Wh, bh, lhW, lhb,
                                                   W1, Wct, W1t, bzp, bhp);
    degcnt_init<<<NBLK, 256, 0, stream>>>(degcnt);
    deg_scatter_fill<<<(NE + 255) / 256, 256, 0, stream>>>(g_src, g_dst, ew, degcnt, csr);
    build_y<<<(NN * 48 + 255) / 256, 256, 0, stream>>>(x, degcnt, yh, dinv, cnt);
    gather_agg<<<(NN * 8 + 255) / 256, 256, 0, stream>>>(cnt, csr, dinv, yh, aggh);
    node_kernel<<<512, 256, 0, stream>>>(aggh, Wct, W1t, bzp, bhp, b1, abh);
    edge_kernel<<<(NE * 8 + 255) / 256, 256, 0, stream>>>(abh, esrc, edst, W2, b2, out);
}

// Round 9
// 265.536 us; speedup vs baseline: 1.0849x; 1.0849x over previous
//
#include <hip/hip_runtime.h>
#include <hip/hip_bf16.h>
#include <hip/hip_fp16.h>

#define NN 100000
#define NE 1600000
#define FI 80
#define HD 64
#define NBLK 391  // ceil(NN/256)

typedef _Float16 f16x8 __attribute__((ext_vector_type(8)));
typedef float f32x4 __attribute__((ext_vector_type(4)));

// ---------------- fused weight precompute ----------------
// Wc_t[j][k] (fp16, [128][96], k>=80 zero): j<64: (Wz@lzW[0:64])[k][j]; j>=64: (Wh@lhW[0:64])[k][j-64]
// W1_t[j][k] (fp16, [128][64]): j<64: W1[k][j]; j>=64: W1[64+k][j-64]  (mlp_W1 is (128,64), stride 64)
// bzp/bhp = fused gate biases (f32).  (H=0 => R-gate dead; softmax(1)=1 => attention dead)
__global__ void fuse_weights(const float* __restrict__ Wz, const float* __restrict__ bz,
                             const float* __restrict__ lzW, const float* __restrict__ lzb,
                             const float* __restrict__ Wh, const float* __restrict__ bh,
                             const float* __restrict__ lhW, const float* __restrict__ lhb,
                             const float* __restrict__ W1,
                             _Float16* __restrict__ Wct, _Float16* __restrict__ W1t,
                             float* __restrict__ bzp, float* __restrict__ bhp) {
    int j = blockIdx.x;      // 0..127 output col
    int k = threadIdx.x;     // 0..127
    if (blockIdx.y == 1) {
        if (k < HD) {
            float v = (j < HD) ? W1[k * HD + j] : W1[(HD + k) * HD + (j - HD)];
            W1t[j * HD + k] = (_Float16)v;
        }
        return;
    }
    bool isZ = j < 64;
    int jj = isZ ? j : j - 64;
    const float* W = isZ ? Wz : Wh;
    const float* L = isZ ? lzW : lhW;
    if (k < FI) {
        float acc = 0.f;
        for (int i = 0; i < HD; ++i) acc = fmaf(W[k * HD + i], L[i * HD + jj], acc);
        Wct[j * 96 + k] = (_Float16)acc;
    } else if (k < 96) {
        Wct[j * 96 + k] = (_Float16)0.f;
    } else if (k == 96) {
        const float* bb = isZ ? bz : bh;
        const float* lb = isZ ? lzb : lhb;
        float acc = lb[jj];
        for (int i = 0; i < HD; ++i) acc = fmaf(bb[i], L[i * HD + jj], acc);
        (isZ ? bzp : bhp)[jj] = acc;
    }
}

// ---------------- degree+count+rank in ONE u32 atomic ----------------
// bits[26:31]=count (cnt<=63: Poisson(16) tail P~1e-14 over 100K nodes), bits[0:25]=sum(ew)
// in 2^-20 fixed point (63*2^20 < 2^26, no carry). Returned old>>26 = per-dst rank (u8).
__global__ void deg_scatter(const int* __restrict__ dst, const float* __restrict__ ew,
                            unsigned* degcnt, unsigned char* __restrict__ rank) {
    int e = blockIdx.x * 256 + threadIdx.x;
    if (e < NE) {
        int d = dst[e];
        unsigned val = (1u << 26) | (unsigned)(ew[e] * 1048576.0f + 0.5f);
        unsigned old = atomicAdd(&degcnt[d], val);
        rank[e] = (unsigned char)(old >> 26);
    }
}

// ---------------- y table (y[n]=dinv[n]*x[n], fp16, 96-half rows) + fused decode ----------------
__global__ void build_y(const float* __restrict__ x, const unsigned* __restrict__ degcnt,
                        ushort* __restrict__ yh, float* __restrict__ dinv, int* __restrict__ cnt) {
    int i = blockIdx.x * 256 + threadIdx.x;   // over NN*48 half2
    if (i >= NN * 48) return;
    int n = i / 48, p = i % 48;
    unsigned v = degcnt[n];
    float deg = 1.0f + (float)(v & 0x03FFFFFFu) * (1.0f / 1048576.0f);
    float di = rsqrtf(deg);
    if (p == 0) { dinv[n] = di; cnt[n] = (int)(v >> 26); }
    __half2 h;
    if (p < 40) {
        float2 vv = *(const float2*)(x + (size_t)n * FI + 2 * p);
        h = __floats2half2_rn(di * vv.x, di * vv.y);
    } else {
        h = __floats2half2_rn(0.f, 0.f);
    }
    *(__half2*)(yh + (size_t)n * 96 + 2 * p) = h;
}

// ---------------- CSR rowstart: hierarchical exclusive scan ----------------
__global__ void scan1(const int* __restrict__ cnt, int* rowstart, int* bsums) {
    __shared__ int s[256];
    int i = blockIdx.x * 256 + threadIdx.x;
    int v = (i < NN) ? cnt[i] : 0;
    s[threadIdx.x] = v;
    __syncthreads();
    for (int off = 1; off < 256; off <<= 1) {
        int t = 0;
        if (threadIdx.x >= off) t = s[threadIdx.x - off];
        __syncthreads();
        s[threadIdx.x] += t;
        __syncthreads();
    }
    if (i < NN) rowstart[i] = s[threadIdx.x] - v;
    if (threadIdx.x == 255) bsums[blockIdx.x] = s[255];
}

__global__ void scan2(int* bsums) {
    __shared__ int s[512];
    int v = (threadIdx.x < NBLK) ? bsums[threadIdx.x] : 0;
    s[threadIdx.x] = v;
    __syncthreads();
    for (int off = 1; off < 512; off <<= 1) {
        int t = 0;
        if (threadIdx.x >= off) t = s[threadIdx.x - off];
        __syncthreads();
        s[threadIdx.x] += t;
        __syncthreads();
    }
    if (threadIdx.x < NBLK) bsums[threadIdx.x] = s[threadIdx.x] - v;
}

__global__ void scan3(int* rowstart, const int* __restrict__ bsums) {
    int i = blockIdx.x * 256 + threadIdx.x;
    if (i < NN) rowstart[i] += bsums[blockIdx.x];
}

// ---------------- CSR fill: NO atomics; 4B entry = (src<<15)|ew_q15 into DENSE 6.4MB table ----------------
// (dense table stays within per-XCD L2 reach -> random stores merge; R8's 25.6MB capped layout thrashed)
__global__ void csr_fill(const int* __restrict__ gsrc, const int* __restrict__ gdst,
                         const float* __restrict__ ew,
                         const int* __restrict__ rowstart,
                         const unsigned char* __restrict__ rank,
                         unsigned* __restrict__ csr) {
    int e = blockIdx.x * 256 + threadIdx.x;
    if (e >= NE) return;
    int s = gsrc[e], d = gdst[e];
    int pos = rowstart[d] + (int)rank[e];
    unsigned q = (unsigned)(ew[e] * 32767.0f + 0.5f);   // ew in [0,1) -> <= 32767
    csr[pos] = ((unsigned)s << 15) | q;
}

// ---------------- gather aggregation ----------------
// acc = y[n] + sum ew*y[src];  agg[n] = dinv[n]*acc  (fp16 out)
__global__ __launch_bounds__(256) void gather_agg(const int* __restrict__ rowstart,
                                                  const int* __restrict__ cnt,
                                                  const unsigned* __restrict__ csr,
                                                  const float* __restrict__ dinv,
                                                  const ushort* __restrict__ yh,
                                                  ushort* __restrict__ aggh) {
    int t = blockIdx.x * 256 + threadIdx.x;
    int n = t >> 3, k = t & 7;
    if (n >= NN) return;
    float di = dinv[n];
    const ushort* yn = yh + (size_t)n * 96;
    float2 acc[5];
#pragma unroll
    for (int j = 0; j < 5; ++j)
        acc[j] = __half22float2(*(const __half2*)(yn + 2 * k + 16 * j));
    int beg = rowstart[n], end = beg + cnt[n];
    for (int i = beg; i < end; ++i) {
        unsigned ent = csr[i];                 // lane-uniform within 8-lane group
        float c = (float)(ent & 0x7FFFu) * (1.0f / 32767.0f);
        const ushort* ys = yh + (size_t)(ent >> 15) * 96;
#pragma unroll
        for (int j = 0; j < 5; ++j) {
            float2 v = __half22float2(*(const __half2*)(ys + 2 * k + 16 * j));
            acc[j].x = fmaf(c, v.x, acc[j].x);
            acc[j].y = fmaf(c, v.y, acc[j].y);
        }
    }
    ushort* an = aggh + (size_t)n * FI;
#pragma unroll
    for (int j = 0; j < 5; ++j)
        *(__half2*)(an + 2 * k + 16 * j) = __floats2half2_rn(di * acc[j].x, di * acc[j].y);
}

// ---------------- node kernel: MFMA fp16 two-stage GEMM ----------------
// GEMM1: u(16x80,fp16) @ Wc(80x128) -> gates -> h(16x64);  GEMM2: h @ W1(64x128) -> ab fp16
// C-layout: col=lane&15, row=(lane>>4)*4+r (m89-verified); k-perm consistent on A/B sides.
__global__ __launch_bounds__(256) void node_kernel(const ushort* __restrict__ aggh,
        const _Float16* __restrict__ Wct, const _Float16* __restrict__ W1t,
        const float* __restrict__ bzp, const float* __restrict__ bhp,
        const float* __restrict__ b1, ushort* __restrict__ abh) {
    __shared__ __align__(16) _Float16 sWc[128 * 104];   // stride 104 halves: 16B-aligned rows
    __shared__ __align__(16) _Float16 sW1[128 * 72];    // stride 72
    __shared__ __align__(16) _Float16 wbuf[4][2176];    // per-wave: h (stride 72) / out (stride 136)
    int tid = threadIdx.x;
    for (int i = tid; i < 1536; i += 256) {
        int col = i / 12, ko = (i % 12) * 8;
        *(uint4*)&sWc[col * 104 + ko] = ((const uint4*)Wct)[i];
    }
    for (int i = tid; i < 1024; i += 256) {
        int col = i / 8, ko = (i % 8) * 8;
        *(uint4*)&sW1[col * 72 + ko] = ((const uint4*)W1t)[i];
    }
    __syncthreads();

    int lane = tid & 63, wv = tid >> 6;
    int q = lane & 15, kg = lane >> 4;
    _Float16* hwb = wbuf[wv];

    float bzc[4], bhc[4], b1c[4];
#pragma unroll
    for (int t = 0; t < 4; ++t) {
        bzc[t] = bzp[q + 16 * t];
        bhc[t] = bhp[q + 16 * t];
        b1c[t] = b1[q + 16 * t];
    }

    const int NT = (NN + 63) >> 6;
    for (int tile = blockIdx.x; tile < NT; tile += gridDim.x) {
        int m0 = tile * 64 + wv * 16;
        int node = m0 + q;
        bool rv = node < NN;
        const _Float16* up = (const _Float16*)(aggh + (size_t)node * FI);
        f16x8 a1[3];
#pragma unroll
        for (int ks = 0; ks < 3; ++ks) {
            int kk = ks * 32 + kg * 8;
            a1[ks] = (rv && kk < FI) ? *(const f16x8*)(up + kk) : f16x8{};
        }
        f32x4 acc[8];
#pragma unroll
        for (int t = 0; t < 8; ++t) {
            const _Float16* wp = &sWc[(q + 16 * t) * 104 + kg * 8];
            f32x4 a = {0.f, 0.f, 0.f, 0.f};
            a = __builtin_amdgcn_mfma_f32_16x16x32_f16(a1[0], *(const f16x8*)(wp), a, 0, 0, 0);
            a = __builtin_amdgcn_mfma_f32_16x16x32_f16(a1[1], *(const f16x8*)(wp + 32), a, 0, 0, 0);
            a = __builtin_amdgcn_mfma_f32_16x16x32_f16(a1[2], *(const f16x8*)(wp + 64), a, 0, 0, 0);
            acc[t] = a;
        }
        // gates: cols 0..63 = Z-pre (acc[0..3]), 64..127 = H-pre (acc[4..7])
#pragma unroll
        for (int t = 0; t < 4; ++t) {
#pragma unroll
            for (int r = 0; r < 4; ++r) {
                float z = acc[t][r] + bzc[t];
                float p = acc[t + 4][r] + bhc[t];
                float Z = 1.f / (1.f + __expf(-z));
                float p2 = fminf(fmaxf(2.f * p, -60.f), 60.f);
                float e2 = __expf(p2);
                float Ht = (e2 - 1.f) / (e2 + 1.f);
                hwb[(kg * 4 + r) * 72 + q + 16 * t] = (_Float16)((1.f - Z) * Ht);
            }
        }
        f16x8 a2[2];
        a2[0] = *(const f16x8*)&hwb[q * 72 + kg * 8];
        a2[1] = *(const f16x8*)&hwb[q * 72 + 32 + kg * 8];
#pragma unroll
        for (int t = 0; t < 8; ++t) {
            const _Float16* wp = &sW1[(q + 16 * t) * 72 + kg * 8];
            f32x4 a = {0.f, 0.f, 0.f, 0.f};
            a = __builtin_amdgcn_mfma_f32_16x16x32_f16(a2[0], *(const f16x8*)(wp), a, 0, 0, 0);
            a = __builtin_amdgcn_mfma_f32_16x16x32_f16(a2[1], *(const f16x8*)(wp + 32), a, 0, 0, 0);
            float bb = (t < 4) ? b1c[t] : 0.f;   // b-part (cols 64..127) has no bias
#pragma unroll
            for (int r = 0; r < 4; ++r)
                hwb[(kg * 4 + r) * 136 + q + 16 * t] = (_Float16)(a[r] + bb);
        }
        // coalesced copy-out: 16 nodes x 128 halves
#pragma unroll
        for (int i = lane; i < 256; i += 64) {
            int nd = i >> 4, off = (i & 15) * 8;
            int n2 = m0 + nd;
            if (n2 < NN)
                *(uint4*)(abh + (size_t)n2 * 128 + off) = *(const uint4*)&hwb[nd * 136 + off];
        }
    }
}

// ---------------- edge classifier: 8 lanes/edge, fp16 gathers ----------------
__global__ __launch_bounds__(256) void edge_kernel(const ushort* __restrict__ abh,
                                                   const int* __restrict__ esrc, const int* __restrict__ edst,
                                                   const float* __restrict__ W2, const float* __restrict__ b2,
                                                   float* __restrict__ out) {
    int t = blockIdx.x * 256 + threadIdx.x;
    int e = t >> 3, q = t & 7;
    if (e >= NE) return;
    int s = esrc[e], d = edst[e];
    uint4 a4 = *(const uint4*)(abh + (size_t)s * 128 + q * 8);
    uint4 b4 = *(const uint4*)(abh + (size_t)d * 128 + 64 + q * 8);
    const __half2* ah = (const __half2*)&a4;
    const __half2* bh2 = (const __half2*)&b4;
    const float4* wv = (const float4*)(W2 + q * 16);
    float o0 = 0.f, o1 = 0.f;
#pragma unroll
    for (int j = 0; j < 4; ++j) {
        float2 av = __half22float2(ah[j]);
        float2 bv = __half22float2(bh2[j]);
        float h0 = fmaxf(av.x + bv.x, 0.f);
        float h1 = fmaxf(av.y + bv.y, 0.f);
        float4 w = wv[j];
        o0 = fmaf(h0, w.x, fmaf(h1, w.z, o0));
        o1 = fmaf(h0, w.y, fmaf(h1, w.w, o1));
    }
    o0 += __shfl_xor(o0, 4, 8); o0 += __shfl_xor(o0, 2, 8); o0 += __shfl_xor(o0, 1, 8);
    o1 += __shfl_xor(o1, 4, 8); o1 += __shfl_xor(o1, 2, 8); o1 += __shfl_xor(o1, 1, 8);
    if (q == 0) {
        float2 r;
        r.x = o0 + b2[0];
        r.y = o1 + b2[1];
        *(float2*)(out + (size_t)e * 2) = r;
    }
}

extern "C" void kernel_launch(void* const* d_in, const int* in_sizes, int n_in,
                              void* d_out, int out_size, void* d_ws, size_t ws_size,
                              hipStream_t stream) {
    (void)in_sizes; (void)n_in; (void)out_size; (void)ws_size;
    const float* x    = (const float*)d_in[0];
    const int*   ei   = (const int*)d_in[1];
    const float* ew   = (const float*)d_in[2];
    const int*   esrc = (const int*)d_in[3];
    const int*   edst = (const int*)d_in[4];
    const float* Wz   = (const float*)d_in[6];
    const float* bz   = (const float*)d_in[7];
    const float* lzW  = (const float*)d_in[8];
    const float* lzb  = (const float*)d_in[9];
    const float* Wh   = (const float*)d_in[14];
    const float* bh   = (const float*)d_in[15];
    const float* lhW  = (const float*)d_in[16];
    const float* lhb  = (const float*)d_in[17];
    const float* W1   = (const float*)d_in[18];
    const float* b1   = (const float*)d_in[19];
    const float* W2   = (const float*)d_in[20];
    const float* b2   = (const float*)d_in[21];
    float* out = (float*)d_out;

    float* ws = (float*)d_ws;
    float* bzp = ws;                                     // 64
    float* bhp = ws + 64;                                // 64
    _Float16* Wct = (_Float16*)(ws + 128);               // 12288 halves
    _Float16* W1t = (_Float16*)(ws + 6272);              // 8192 halves
    unsigned* degcnt = (unsigned*)(ws + 10368);          // 100K u32
    float* dinv     = ws + 110368;                       // 100K f32
    int*   cnt      = (int*)(ws + 210368);               // 100K i32
    int*   rowstart = (int*)(ws + 310368);               // 100K i32
    int*   bsums    = (int*)(ws + 410368);               // 512
    ushort* yh   = (ushort*)(ws + 410880);               // 9.6M halves (100K x 96), 16B aligned
    ushort* aggh = (ushort*)(ws + 5210880);              // 8M halves (100K x 80), 16B aligned
    unsigned char* rank = (unsigned char*)(ws + 9210880);// 1.6M u8 (live: deg_scatter..csr_fill)
    unsigned* csr  = (unsigned*)(ws + 9610880);          // 1.6M u32 dense CSR (live: csr_fill..gather)
    ushort* abh = (ushort*)(ws + 9210880);               // 12.8M halves (live: node..edge), aliases rank+csr

    const int* g_src = ei;
    const int* g_dst = ei + NE;

    fuse_weights<<<dim3(128, 2), 128, 0, stream>>>(Wz, bz, lzW, lzb, Wh, bh, lhW, lhb,
                                                   W1, Wct, W1t, bzp, bhp);
    hipMemsetAsync(degcnt, 0, NN * sizeof(unsigned), stream);
    deg_scatter<<<(NE + 255) / 256, 256, 0, stream>>>(g_dst, ew, degcnt, rank);
    build_y<<<(NN * 48 + 255) / 256, 256, 0, stream>>>(x, degcnt, yh, dinv, cnt);
    scan1<<<NBLK, 256, 0, stream>>>(cnt, rowstart, bsums);
    scan2<<<1, 512, 0, stream>>>(bsums);
    scan3<<<NBLK, 256, 0, stream>>>(rowstart, bsums);
    csr_fill<<<(NE + 255) / 256, 256, 0, stream>>>(g_src, g_dst, ew, rowstart, rank, csr);
    gather_agg<<<(NN * 8 + 255) / 256, 256, 0, stream>>>(rowstart, cnt, csr, dinv, yh, aggh);
    node_kernel<<<512, 256, 0, stream>>>(aggh, Wct, W1t, bzp, bhp, b1, abh);
    edge_kernel<<<(NE * 8 + 255) / 256, 256, 0, stream>>>(abh, esrc, edst, W2, b2, out);
}

// Round 10
// 248.807 us; speedup vs baseline: 1.1578x; 1.0672x over previous
//
#include <hip/hip_runtime.h>
#include <hip/hip_bf16.h>
#include <hip/hip_fp16.h>

#define NN 100000
#define NE 1600000
#define FI 80
#define HD 64
#define NBLK 391  // ceil(NN/256)

typedef _Float16 f16x8 __attribute__((ext_vector_type(8)));
typedef float f32x4 __attribute__((ext_vector_type(4)));

// ---------------- fused weight precompute ----------------
// Wc_t[j][k] (fp16, [128][96], k>=80 zero): j<64: (Wz@lzW[0:64])[k][j]; j>=64: (Wh@lhW[0:64])[k][j-64]
// W1_t[j][k] (fp16, [128][64]): j<64: W1[k][j]; j>=64: W1[64+k][j-64]  (mlp_W1 is (128,64), stride 64)
// bzp/bhp = fused gate biases (f32).  (H=0 => R-gate dead; softmax(1)=1 => attention dead)
__global__ void fuse_weights(const float* __restrict__ Wz, const float* __restrict__ bz,
                             const float* __restrict__ lzW, const float* __restrict__ lzb,
                             const float* __restrict__ Wh, const float* __restrict__ bh,
                             const float* __restrict__ lhW, const float* __restrict__ lhb,
                             const float* __restrict__ W1,
                             _Float16* __restrict__ Wct, _Float16* __restrict__ W1t,
                             float* __restrict__ bzp, float* __restrict__ bhp) {
    int j = blockIdx.x;      // 0..127 output col
    int k = threadIdx.x;     // 0..127
    if (blockIdx.y == 1) {
        if (k < HD) {
            float v = (j < HD) ? W1[k * HD + j] : W1[(HD + k) * HD + (j - HD)];
            W1t[j * HD + k] = (_Float16)v;
        }
        return;
    }
    bool isZ = j < 64;
    int jj = isZ ? j : j - 64;
    const float* W = isZ ? Wz : Wh;
    const float* L = isZ ? lzW : lhW;
    if (k < FI) {
        float acc = 0.f;
        for (int i = 0; i < HD; ++i) acc = fmaf(W[k * HD + i], L[i * HD + jj], acc);
        Wct[j * 96 + k] = (_Float16)acc;
    } else if (k < 96) {
        Wct[j * 96 + k] = (_Float16)0.f;
    } else if (k == 96) {
        const float* bb = isZ ? bz : bh;
        const float* lb = isZ ? lzb : lhb;
        float acc = lb[jj];
        for (int i = 0; i < HD; ++i) acc = fmaf(bb[i], L[i * HD + jj], acc);
        (isZ ? bzp : bhp)[jj] = acc;
    }
}

// ---------------- degree+count+rank in ONE u32 atomic ----------------
// bits[26:31]=count (cnt<=63: Poisson(16) tail P~1e-14 over 100K nodes), bits[0:25]=sum(ew)
// in 2^-20 fixed point (63*2^20 < 2^26, no carry). Returned old>>26 = per-dst rank (u8).
__global__ void deg_scatter(const int* __restrict__ dst, const float* __restrict__ ew,
                            unsigned* degcnt, unsigned char* __restrict__ rank) {
    int e = blockIdx.x * 256 + threadIdx.x;
    if (e < NE) {
        int d = dst[e];
        unsigned val = (1u << 26) | (unsigned)(ew[e] * 1048576.0f + 0.5f);
        unsigned old = atomicAdd(&degcnt[d], val);
        rank[e] = (unsigned char)(old >> 26);
    }
}

// ---------------- y table (y[n]=dinv[n]*x[n], fp16, 96-half rows) + fused decode ----------------
__global__ void build_y(const float* __restrict__ x, const unsigned* __restrict__ degcnt,
                        ushort* __restrict__ yh, float* __restrict__ dinv, int* __restrict__ cnt) {
    int i = blockIdx.x * 256 + threadIdx.x;   // over NN*48 half2
    if (i >= NN * 48) return;
    int n = i / 48, p = i % 48;
    unsigned v = degcnt[n];
    float deg = 1.0f + (float)(v & 0x03FFFFFFu) * (1.0f / 1048576.0f);
    float di = rsqrtf(deg);
    if (p == 0) { dinv[n] = di; cnt[n] = (int)(v >> 26); }
    __half2 h;
    if (p < 40) {
        float2 vv = *(const float2*)(x + (size_t)n * FI + 2 * p);
        h = __floats2half2_rn(di * vv.x, di * vv.y);
    } else {
        h = __floats2half2_rn(0.f, 0.f);
    }
    *(__half2*)(yh + (size_t)n * 96 + 2 * p) = h;
}

// ---------------- CSR rowstart: hierarchical exclusive scan ----------------
__global__ void scan1(const int* __restrict__ cnt, int* rowstart, int* bsums) {
    __shared__ int s[256];
    int i = blockIdx.x * 256 + threadIdx.x;
    int v = (i < NN) ? cnt[i] : 0;
    s[threadIdx.x] = v;
    __syncthreads();
    for (int off = 1; off < 256; off <<= 1) {
        int t = 0;
        if (threadIdx.x >= off) t = s[threadIdx.x - off];
        __syncthreads();
        s[threadIdx.x] += t;
        __syncthreads();
    }
    if (i < NN) rowstart[i] = s[threadIdx.x] - v;
    if (threadIdx.x == 255) bsums[blockIdx.x] = s[255];
}

__global__ void scan2(int* bsums) {
    __shared__ int s[512];
    int v = (threadIdx.x < NBLK) ? bsums[threadIdx.x] : 0;
    s[threadIdx.x] = v;
    __syncthreads();
    for (int off = 1; off < 512; off <<= 1) {
        int t = 0;
        if (threadIdx.x >= off) t = s[threadIdx.x - off];
        __syncthreads();
        s[threadIdx.x] += t;
        __syncthreads();
    }
    if (threadIdx.x < NBLK) bsums[threadIdx.x] = s[threadIdx.x] - v;
}

__global__ void scan3(int* rowstart, const int* __restrict__ bsums) {
    int i = blockIdx.x * 256 + threadIdx.x;
    if (i < NN) rowstart[i] += bsums[blockIdx.x];
}

// ---------------- CSR fill: NO atomics; 4B entry = (src<<15)|ew_q15 into DENSE 6.4MB table ----------------
__global__ void csr_fill(const int* __restrict__ gsrc, const int* __restrict__ gdst,
                         const float* __restrict__ ew,
                         const int* __restrict__ rowstart,
                         const unsigned char* __restrict__ rank,
                         unsigned* __restrict__ csr) {
    int e = blockIdx.x * 256 + threadIdx.x;
    if (e >= NE) return;
    int s = gsrc[e], d = gdst[e];
    int pos = rowstart[d] + (int)rank[e];
    unsigned q = (unsigned)(ew[e] * 32767.0f + 0.5f);   // ew in [0,1) -> <= 32767
    csr[pos] = ((unsigned)s << 15) | q;
}

// ---------------- gather aggregation (csr entry prefetched 1 ahead to break latency chain) ----------------
// acc = y[n] + sum ew*y[src];  agg[n] = dinv[n]*acc  (fp16 out)
__global__ __launch_bounds__(256) void gather_agg(const int* __restrict__ rowstart,
                                                  const int* __restrict__ cnt,
                                                  const unsigned* __restrict__ csr,
                                                  const float* __restrict__ dinv,
                                                  const ushort* __restrict__ yh,
                                                  ushort* __restrict__ aggh) {
    int t = blockIdx.x * 256 + threadIdx.x;
    int n = t >> 3, k = t & 7;
    if (n >= NN) return;
    float di = dinv[n];
    const ushort* yn = yh + (size_t)n * 96;
    float2 acc[5];
#pragma unroll
    for (int j = 0; j < 5; ++j)
        acc[j] = __half22float2(*(const __half2*)(yn + 2 * k + 16 * j));
    int beg = rowstart[n], end = beg + cnt[n];
    unsigned ent = (beg < end) ? csr[beg] : 0u;
    for (int i = beg; i < end; ++i) {
        unsigned cur = ent;
        if (i + 1 < end) ent = csr[i + 1];     // prefetch next entry (overlaps y-row fetch below)
        float c = (float)(cur & 0x7FFFu) * (1.0f / 32767.0f);
        const ushort* ys = yh + (size_t)(cur >> 15) * 96;
#pragma unroll
        for (int j = 0; j < 5; ++j) {
            float2 v = __half22float2(*(const __half2*)(ys + 2 * k + 16 * j));
            acc[j].x = fmaf(c, v.x, acc[j].x);
            acc[j].y = fmaf(c, v.y, acc[j].y);
        }
    }
    ushort* an = aggh + (size_t)n * FI;
#pragma unroll
    for (int j = 0; j < 5; ++j)
        *(__half2*)(an + 2 * k + 16 * j) = __floats2half2_rn(di * acc[j].x, di * acc[j].y);
}

// ---------------- node kernel: MFMA fp16 two-stage GEMM ----------------
// GEMM1: u(16x80,fp16) @ Wc(80x128) -> gates -> h(16x64);  GEMM2: h @ W1(64x128) -> ab fp16
// C-layout: col=lane&15, row=(lane>>4)*4+r (m89-verified); k-perm consistent on A/B sides.
__global__ __launch_bounds__(256) void node_kernel(const ushort* __restrict__ aggh,
        const _Float16* __restrict__ Wct, const _Float16* __restrict__ W1t,
        const float* __restrict__ bzp, const float* __restrict__ bhp,
        const float* __restrict__ b1, ushort* __restrict__ abh) {
    __shared__ __align__(16) _Float16 sWc[128 * 104];   // stride 104 halves: 16B-aligned rows
    __shared__ __align__(16) _Float16 sW1[128 * 72];    // stride 72
    __shared__ __align__(16) _Float16 wbuf[4][2176];    // per-wave: h (stride 72) / out (stride 136)
    int tid = threadIdx.x;
    for (int i = tid; i < 1536; i += 256) {
        int col = i / 12, ko = (i % 12) * 8;
        *(uint4*)&sWc[col * 104 + ko] = ((const uint4*)Wct)[i];
    }
    for (int i = tid; i < 1024; i += 256) {
        int col = i / 8, ko = (i % 8) * 8;
        *(uint4*)&sW1[col * 72 + ko] = ((const uint4*)W1t)[i];
    }
    __syncthreads();

    int lane = tid & 63, wv = tid >> 6;
    int q = lane & 15, kg = lane >> 4;
    _Float16* hwb = wbuf[wv];

    float bzc[4], bhc[4], b1c[4];
#pragma unroll
    for (int t = 0; t < 4; ++t) {
        bzc[t] = bzp[q + 16 * t];
        bhc[t] = bhp[q + 16 * t];
        b1c[t] = b1[q + 16 * t];
    }

    const int NT = (NN + 63) >> 6;
    for (int tile = blockIdx.x; tile < NT; tile += gridDim.x) {
        int m0 = tile * 64 + wv * 16;
        int node = m0 + q;
        bool rv = node < NN;
        const _Float16* up = (const _Float16*)(aggh + (size_t)node * FI);
        f16x8 a1[3];
#pragma unroll
        for (int ks = 0; ks < 3; ++ks) {
            int kk = ks * 32 + kg * 8;
            a1[ks] = (rv && kk < FI) ? *(const f16x8*)(up + kk) : f16x8{};
        }
        f32x4 acc[8];
#pragma unroll
        for (int t = 0; t < 8; ++t) {
            const _Float16* wp = &sWc[(q + 16 * t) * 104 + kg * 8];
            f32x4 a = {0.f, 0.f, 0.f, 0.f};
            a = __builtin_amdgcn_mfma_f32_16x16x32_f16(a1[0], *(const f16x8*)(wp), a, 0, 0, 0);
            a = __builtin_amdgcn_mfma_f32_16x16x32_f16(a1[1], *(const f16x8*)(wp + 32), a, 0, 0, 0);
            a = __builtin_amdgcn_mfma_f32_16x16x32_f16(a1[2], *(const f16x8*)(wp + 64), a, 0, 0, 0);
            acc[t] = a;
        }
        // gates: cols 0..63 = Z-pre (acc[0..3]), 64..127 = H-pre (acc[4..7])
#pragma unroll
        for (int t = 0; t < 4; ++t) {
#pragma unroll
            for (int r = 0; r < 4; ++r) {
                float z = acc[t][r] + bzc[t];
                float p = acc[t + 4][r] + bhc[t];
                float Z = 1.f / (1.f + __expf(-z));
                float p2 = fminf(fmaxf(2.f * p, -60.f), 60.f);
                float e2 = __expf(p2);
                float Ht = (e2 - 1.f) / (e2 + 1.f);
                hwb[(kg * 4 + r) * 72 + q + 16 * t] = (_Float16)((1.f - Z) * Ht);
            }
        }
        f16x8 a2[2];
        a2[0] = *(const f16x8*)&hwb[q * 72 + kg * 8];
        a2[1] = *(const f16x8*)&hwb[q * 72 + 32 + kg * 8];
#pragma unroll
        for (int t = 0; t < 8; ++t) {
            const _Float16* wp = &sW1[(q + 16 * t) * 72 + kg * 8];
            f32x4 a = {0.f, 0.f, 0.f, 0.f};
            a = __builtin_amdgcn_mfma_f32_16x16x32_f16(a2[0], *(const f16x8*)(wp), a, 0, 0, 0);
            a = __builtin_amdgcn_mfma_f32_16x16x32_f16(a2[1], *(const f16x8*)(wp + 32), a, 0, 0, 0);
            float bb = (t < 4) ? b1c[t] : 0.f;   // b-part (cols 64..127) has no bias
#pragma unroll
            for (int r = 0; r < 4; ++r)
                hwb[(kg * 4 + r) * 136 + q + 16 * t] = (_Float16)(a[r] + bb);
        }
        // coalesced copy-out: 16 nodes x 128 halves
#pragma unroll
        for (int i = lane; i < 256; i += 64) {
            int nd = i >> 4, off = (i & 15) * 8;
            int n2 = m0 + nd;
            if (n2 < NN)
                *(uint4*)(abh + (size_t)n2 * 128 + off) = *(const uint4*)&hwb[nd * 136 + off];
        }
    }
}

// ---------------- edge classifier: 8 lanes/edge, TWO edges per group (dual gather chains) ----------------
__global__ __launch_bounds__(256) void edge_kernel(const ushort* __restrict__ abh,
                                                   const int* __restrict__ esrc, const int* __restrict__ edst,
                                                   const float* __restrict__ W2, const float* __restrict__ b2,
                                                   float* __restrict__ out) {
    const int HALF = NE / 2;
    int t = blockIdx.x * 256 + threadIdx.x;
    int g = t >> 3, q = t & 7;
    if (g >= HALF) return;
    int e0 = g, e1 = g + HALF;
    int s0 = esrc[e0], d0 = edst[e0];
    int s1 = esrc[e1], d1 = edst[e1];
    // 4 independent gather chains in flight
    uint4 a40 = *(const uint4*)(abh + (size_t)s0 * 128 + q * 8);
    uint4 b40 = *(const uint4*)(abh + (size_t)d0 * 128 + 64 + q * 8);
    uint4 a41 = *(const uint4*)(abh + (size_t)s1 * 128 + q * 8);
    uint4 b41 = *(const uint4*)(abh + (size_t)d1 * 128 + 64 + q * 8);
    float4 w[4];
#pragma unroll
    for (int j = 0; j < 4; ++j) w[j] = ((const float4*)(W2 + q * 16))[j];
    float c0 = b2[0], c1 = b2[1];

    float o00 = 0.f, o01 = 0.f, o10 = 0.f, o11 = 0.f;
    const __half2* ah0 = (const __half2*)&a40;
    const __half2* bh0 = (const __half2*)&b40;
    const __half2* ah1 = (const __half2*)&a41;
    const __half2* bh1 = (const __half2*)&b41;
#pragma unroll
    for (int j = 0; j < 4; ++j) {
        float2 av = __half22float2(ah0[j]);
        float2 bv = __half22float2(bh0[j]);
        float h0 = fmaxf(av.x + bv.x, 0.f);
        float h1 = fmaxf(av.y + bv.y, 0.f);
        o00 = fmaf(h0, w[j].x, fmaf(h1, w[j].z, o00));
        o01 = fmaf(h0, w[j].y, fmaf(h1, w[j].w, o01));
        float2 av1 = __half22float2(ah1[j]);
        float2 bv1 = __half22float2(bh1[j]);
        float g0 = fmaxf(av1.x + bv1.x, 0.f);
        float g1 = fmaxf(av1.y + bv1.y, 0.f);
        o10 = fmaf(g0, w[j].x, fmaf(g1, w[j].z, o10));
        o11 = fmaf(g0, w[j].y, fmaf(g1, w[j].w, o11));
    }
#pragma unroll
    for (int m = 4; m >= 1; m >>= 1) {
        o00 += __shfl_xor(o00, m, 8);
        o01 += __shfl_xor(o01, m, 8);
        o10 += __shfl_xor(o10, m, 8);
        o11 += __shfl_xor(o11, m, 8);
    }
    if (q == 0) {
        *(float2*)(out + (size_t)e0 * 2) = make_float2(o00 + c0, o01 + c1);
        *(float2*)(out + (size_t)e1 * 2) = make_float2(o10 + c0, o11 + c1);
    }
}

extern "C" void kernel_launch(void* const* d_in, const int* in_sizes, int n_in,
                              void* d_out, int out_size, void* d_ws, size_t ws_size,
                              hipStream_t stream) {
    (void)in_sizes; (void)n_in; (void)out_size; (void)ws_size;
    const float* x    = (const float*)d_in[0];
    const int*   ei   = (const int*)d_in[1];
    const float* ew   = (const float*)d_in[2];
    const int*   esrc = (const int*)d_in[3];
    const int*   edst = (const int*)d_in[4];
    const float* Wz   = (const float*)d_in[6];
    const float* bz   = (const float*)d_in[7];
    const float* lzW  = (const float*)d_in[8];
    const float* lzb  = (const float*)d_in[9];
    const float* Wh   = (const float*)d_in[14];
    const float* bh   = (const float*)d_in[15];
    const float* lhW  = (const float*)d_in[16];
    const float* lhb  = (const float*)d_in[17];
    const float* W1   = (const float*)d_in[18];
    const float* b1   = (const float*)d_in[19];
    const float* W2   = (const float*)d_in[20];
    const float* b2   = (const float*)d_in[21];
    float* out = (float*)d_out;

    float* ws = (float*)d_ws;
    float* bzp = ws;                                     // 64
    float* bhp = ws + 64;                                // 64
    _Float16* Wct = (_Float16*)(ws + 128);               // 12288 halves
    _Float16* W1t = (_Float16*)(ws + 6272);              // 8192 halves
    unsigned* degcnt = (unsigned*)(ws + 10368);          // 100K u32
    float* dinv     = ws + 110368;                       // 100K f32
    int*   cnt      = (int*)(ws + 210368);               // 100K i32
    int*   rowstart = (int*)(ws + 310368);               // 100K i32
    int*   bsums    = (int*)(ws + 410368);               // 512
    ushort* yh   = (ushort*)(ws + 410880);               // 9.6M halves (100K x 96), 16B aligned
    ushort* aggh = (ushort*)(ws + 5210880);              // 8M halves (100K x 80), 16B aligned
    unsigned char* rank = (unsigned char*)(ws + 9210880);// 1.6M u8 (live: deg_scatter..csr_fill)
    unsigned* csr  = (unsigned*)(ws + 9610880);          // 1.6M u32 dense CSR (live: csr_fill..gather)
    ushort* abh = (ushort*)(ws + 9210880);               // 12.8M halves (live: node..edge), aliases rank+csr

    const int* g_src = ei;
    const int* g_dst = ei + NE;

    fuse_weights<<<dim3(128, 2), 128, 0, stream>>>(Wz, bz, lzW, lzb, Wh, bh, lhW, lhb,
                                                   W1, Wct, W1t, bzp, bhp);
    hipMemsetAsync(degcnt, 0, NN * sizeof(unsigned), stream);
    deg_scatter<<<(NE + 255) / 256, 256, 0, stream>>>(g_dst, ew, degcnt, rank);
    build_y<<<(NN * 48 + 255) / 256, 256, 0, stream>>>(x, degcnt, yh, dinv, cnt);
    scan1<<<NBLK, 256, 0, stream>>>(cnt, rowstart, bsums);
    scan2<<<1, 512, 0, stream>>>(bsums);
    scan3<<<NBLK, 256, 0, stream>>>(rowstart, bsums);
    csr_fill<<<(NE + 255) / 256, 256, 0, stream>>>(g_src, g_dst, ew, rowstart, rank, csr);
    gather_agg<<<(NN * 8 + 255) / 256, 256, 0, stream>>>(rowstart, cnt, csr, dinv, yh, aggh);
    node_kernel<<<512, 256, 0, stream>>>(aggh, Wct, W1t, bzp, bhp, b1, abh);
    edge_kernel<<<(NE / 2 * 8 + 255) / 256, 256, 0, stream>>>(abh, esrc, edst, W2, b2, out);
}

// Round 11
// 246.930 us; speedup vs baseline: 1.1666x; 1.0076x over previous
//
#include <hip/hip_runtime.h>
#include <hip/hip_bf16.h>
#include <hip/hip_fp16.h>

#define NN 100000
#define NE 1600000
#define FI 80
#define HD 64
#define NBLK 391  // ceil(NN/256)

typedef _Float16 f16x8 __attribute__((ext_vector_type(8)));
typedef float f32x4 __attribute__((ext_vector_type(4)));

// ---------------- fused weight precompute ----------------
// Wc_t[j][k] (fp16, [128][96], k>=80 zero): j<64: (Wz@lzW[0:64])[k][j]; j>=64: (Wh@lhW[0:64])[k][j-64]
// W1_t[j][k] (fp16, [128][64]): j<64: W1[k][j]; j>=64: W1[64+k][j-64]  (mlp_W1 is (128,64), stride 64)
// bzp/bhp = fused gate biases (f32).  (H=0 => R-gate dead; softmax(1)=1 => attention dead)
__global__ void fuse_weights(const float* __restrict__ Wz, const float* __restrict__ bz,
                             const float* __restrict__ lzW, const float* __restrict__ lzb,
                             const float* __restrict__ Wh, const float* __restrict__ bh,
                             const float* __restrict__ lhW, const float* __restrict__ lhb,
                             const float* __restrict__ W1,
                             _Float16* __restrict__ Wct, _Float16* __restrict__ W1t,
                             float* __restrict__ bzp, float* __restrict__ bhp) {
    int j = blockIdx.x;      // 0..127 output col
    int k = threadIdx.x;     // 0..127
    if (blockIdx.y == 1) {
        if (k < HD) {
            float v = (j < HD) ? W1[k * HD + j] : W1[(HD + k) * HD + (j - HD)];
            W1t[j * HD + k] = (_Float16)v;
        }
        return;
    }
    bool isZ = j < 64;
    int jj = isZ ? j : j - 64;
    const float* W = isZ ? Wz : Wh;
    const float* L = isZ ? lzW : lhW;
    if (k < FI) {
        float acc = 0.f;
        for (int i = 0; i < HD; ++i) acc = fmaf(W[k * HD + i], L[i * HD + jj], acc);
        Wct[j * 96 + k] = (_Float16)acc;
    } else if (k < 96) {
        Wct[j * 96 + k] = (_Float16)0.f;
    } else if (k == 96) {
        const float* bb = isZ ? bz : bh;
        const float* lb = isZ ? lzb : lhb;
        float acc = lb[jj];
        for (int i = 0; i < HD; ++i) acc = fmaf(bb[i], L[i * HD + jj], acc);
        (isZ ? bzp : bhp)[jj] = acc;
    }
}

// ---------------- degree+count+rank in ONE u32 atomic, LINE-PADDED table ----------------
// degcnt[n<<4]: one 64-B line per node -> only a node's own ~16 edges contend per line
// (R10 diag: 400KB packed table => ~256 atomics serializing per line, 24 Gops/s).
// bits[26:31]=count (cnt<=63), bits[0:25]=sum(ew) in 2^-20 fixed (63*2^20 < 2^26, no carry).
__global__ void deg_scatter(const int* __restrict__ dst, const float* __restrict__ ew,
                            unsigned* degcnt, unsigned char* __restrict__ rank) {
    int e = blockIdx.x * 256 + threadIdx.x;
    if (e < NE) {
        int d = dst[e];
        unsigned val = (1u << 26) | (unsigned)(ew[e] * 1048576.0f + 0.5f);
        unsigned old = atomicAdd(&degcnt[(unsigned)d << 4], val);
        rank[e] = (unsigned char)(old >> 26);
    }
}

// ---------------- y table (y[n]=dinv[n]*x[n], fp16, 96-half rows) + fused decode ----------------
__global__ void build_y(const float* __restrict__ x, const unsigned* __restrict__ degcnt,
                        ushort* __restrict__ yh, float* __restrict__ dinv, int* __restrict__ cnt) {
    int i = blockIdx.x * 256 + threadIdx.x;   // over NN*48 half2
    if (i >= NN * 48) return;
    int n = i / 48, p = i % 48;
    unsigned v = degcnt[(unsigned)n << 4];
    float deg = 1.0f + (float)(v & 0x03FFFFFFu) * (1.0f / 1048576.0f);
    float di = rsqrtf(deg);
    if (p == 0) { dinv[n] = di; cnt[n] = (int)(v >> 26); }
    __half2 h;
    if (p < 40) {
        float2 vv = *(const float2*)(x + (size_t)n * FI + 2 * p);
        h = __floats2half2_rn(di * vv.x, di * vv.y);
    } else {
        h = __floats2half2_rn(0.f, 0.f);
    }
    *(__half2*)(yh + (size_t)n * 96 + 2 * p) = h;
}

// ---------------- CSR rowstart: hierarchical exclusive scan ----------------
__global__ void scan1(const int* __restrict__ cnt, int* rowstart, int* bsums) {
    __shared__ int s[256];
    int i = blockIdx.x * 256 + threadIdx.x;
    int v = (i < NN) ? cnt[i] : 0;
    s[threadIdx.x] = v;
    __syncthreads();
    for (int off = 1; off < 256; off <<= 1) {
        int t = 0;
        if (threadIdx.x >= off) t = s[threadIdx.x - off];
        __syncthreads();
        s[threadIdx.x] += t;
        __syncthreads();
    }
    if (i < NN) rowstart[i] = s[threadIdx.x] - v;
    if (threadIdx.x == 255) bsums[blockIdx.x] = s[255];
}

__global__ void scan2(int* bsums) {
    __shared__ int s[512];
    int v = (threadIdx.x < NBLK) ? bsums[threadIdx.x] : 0;
    s[threadIdx.x] = v;
    __syncthreads();
    for (int off = 1; off < 512; off <<= 1) {
        int t = 0;
        if (threadIdx.x >= off) t = s[threadIdx.x - off];
        __syncthreads();
        s[threadIdx.x] += t;
        __syncthreads();
    }
    if (threadIdx.x < NBLK) bsums[threadIdx.x] = s[threadIdx.x] - v;
}

__global__ void scan3(int* rowstart, const int* __restrict__ bsums) {
    int i = blockIdx.x * 256 + threadIdx.x;
    if (i < NN) rowstart[i] += bsums[blockIdx.x];
}

// ---------------- CSR fill: NO atomics; 4B entry = (src<<15)|ew_q15 into DENSE 6.4MB table ----------------
__global__ void csr_fill(const int* __restrict__ gsrc, const int* __restrict__ gdst,
                         const float* __restrict__ ew,
                         const int* __restrict__ rowstart,
                         const unsigned char* __restrict__ rank,
                         unsigned* __restrict__ csr) {
    int e = blockIdx.x * 256 + threadIdx.x;
    if (e >= NE) return;
    int s = gsrc[e], d = gdst[e];
    int pos = rowstart[d] + (int)rank[e];
    unsigned q = (unsigned)(ew[e] * 32767.0f + 0.5f);   // ew in [0,1) -> <= 32767
    csr[pos] = ((unsigned)s << 15) | q;
}

// ---------------- gather aggregation (csr entry prefetched 1 ahead to break latency chain) ----------------
// acc = y[n] + sum ew*y[src];  agg[n] = dinv[n]*acc  (fp16 out)
__global__ __launch_bounds__(256) void gather_agg(const int* __restrict__ rowstart,
                                                  const int* __restrict__ cnt,
                                                  const unsigned* __restrict__ csr,
                                                  const float* __restrict__ dinv,
                                                  const ushort* __restrict__ yh,
                                                  ushort* __restrict__ aggh) {
    int t = blockIdx.x * 256 + threadIdx.x;
    int n = t >> 3, k = t & 7;
    if (n >= NN) return;
    float di = dinv[n];
    const ushort* yn = yh + (size_t)n * 96;
    float2 acc[5];
#pragma unroll
    for (int j = 0; j < 5; ++j)
        acc[j] = __half22float2(*(const __half2*)(yn + 2 * k + 16 * j));
    int beg = rowstart[n], end = beg + cnt[n];
    unsigned ent = (beg < end) ? csr[beg] : 0u;
    for (int i = beg; i < end; ++i) {
        unsigned cur = ent;
        if (i + 1 < end) ent = csr[i + 1];     // prefetch next entry (overlaps y-row fetch below)
        float c = (float)(cur & 0x7FFFu) * (1.0f / 32767.0f);
        const ushort* ys = yh + (size_t)(cur >> 15) * 96;
#pragma unroll
        for (int j = 0; j < 5; ++j) {
            float2 v = __half22float2(*(const __half2*)(ys + 2 * k + 16 * j));
            acc[j].x = fmaf(c, v.x, acc[j].x);
            acc[j].y = fmaf(c, v.y, acc[j].y);
        }
    }
    ushort* an = aggh + (size_t)n * FI;
#pragma unroll
    for (int j = 0; j < 5; ++j)
        *(__half2*)(an + 2 * k + 16 * j) = __floats2half2_rn(di * acc[j].x, di * acc[j].y);
}

// ---------------- node kernel: MFMA fp16 two-stage GEMM ----------------
// GEMM1: u(16x80,fp16) @ Wc(80x128) -> gates -> h(16x64);  GEMM2: h @ W1(64x128) -> ab fp16
// C-layout: col=lane&15, row=(lane>>4)*4+r (m89-verified); k-perm consistent on A/B sides.
__global__ __launch_bounds__(256) void node_kernel(const ushort* __restrict__ aggh,
        const _Float16* __restrict__ Wct, const _Float16* __restrict__ W1t,
        const float* __restrict__ bzp, const float* __restrict__ bhp,
        const float* __restrict__ b1, ushort* __restrict__ abh) {
    __shared__ __align__(16) _Float16 sWc[128 * 104];   // stride 104 halves: 16B-aligned rows
    __shared__ __align__(16) _Float16 sW1[128 * 72];    // stride 72
    __shared__ __align__(16) _Float16 wbuf[4][2176];    // per-wave: h (stride 72) / out (stride 136)
    int tid = threadIdx.x;
    for (int i = tid; i < 1536; i += 256) {
        int col = i / 12, ko = (i % 12) * 8;
        *(uint4*)&sWc[col * 104 + ko] = ((const uint4*)Wct)[i];
    }
    for (int i = tid; i < 1024; i += 256) {
        int col = i / 8, ko = (i % 8) * 8;
        *(uint4*)&sW1[col * 72 + ko] = ((const uint4*)W1t)[i];
    }
    __syncthreads();

    int lane = tid & 63, wv = tid >> 6;
    int q = lane & 15, kg = lane >> 4;
    _Float16* hwb = wbuf[wv];

    float bzc[4], bhc[4], b1c[4];
#pragma unroll
    for (int t = 0; t < 4; ++t) {
        bzc[t] = bzp[q + 16 * t];
        bhc[t] = bhp[q + 16 * t];
        b1c[t] = b1[q + 16 * t];
    }

    const int NT = (NN + 63) >> 6;
    for (int tile = blockIdx.x; tile < NT; tile += gridDim.x) {
        int m0 = tile * 64 + wv * 16;
        int node = m0 + q;
        bool rv = node < NN;
        const _Float16* up = (const _Float16*)(aggh + (size_t)node * FI);
        f16x8 a1[3];
#pragma unroll
        for (int ks = 0; ks < 3; ++ks) {
            int kk = ks * 32 + kg * 8;
            a1[ks] = (rv && kk < FI) ? *(const f16x8*)(up + kk) : f16x8{};
        }
        f32x4 acc[8];
#pragma unroll
        for (int t = 0; t < 8; ++t) {
            const _Float16* wp = &sWc[(q + 16 * t) * 104 + kg * 8];
            f32x4 a = {0.f, 0.f, 0.f, 0.f};
            a = __builtin_amdgcn_mfma_f32_16x16x32_f16(a1[0], *(const f16x8*)(wp), a, 0, 0, 0);
            a = __builtin_amdgcn_mfma_f32_16x16x32_f16(a1[1], *(const f16x8*)(wp + 32), a, 0, 0, 0);
            a = __builtin_amdgcn_mfma_f32_16x16x32_f16(a1[2], *(const f16x8*)(wp + 64), a, 0, 0, 0);
            acc[t] = a;
        }
        // gates: cols 0..63 = Z-pre (acc[0..3]), 64..127 = H-pre (acc[4..7])
#pragma unroll
        for (int t = 0; t < 4; ++t) {
#pragma unroll
            for (int r = 0; r < 4; ++r) {
                float z = acc[t][r] + bzc[t];
                float p = acc[t + 4][r] + bhc[t];
                float Z = 1.f / (1.f + __expf(-z));
                float p2 = fminf(fmaxf(2.f * p, -60.f), 60.f);
                float e2 = __expf(p2);
                float Ht = (e2 - 1.f) / (e2 + 1.f);
                hwb[(kg * 4 + r) * 72 + q + 16 * t] = (_Float16)((1.f - Z) * Ht);
            }
        }
        f16x8 a2[2];
        a2[0] = *(const f16x8*)&hwb[q * 72 + kg * 8];
        a2[1] = *(const f16x8*)&hwb[q * 72 + 32 + kg * 8];
#pragma unroll
        for (int t = 0; t < 8; ++t) {
            const _Float16* wp = &sW1[(q + 16 * t) * 72 + kg * 8];
            f32x4 a = {0.f, 0.f, 0.f, 0.f};
            a = __builtin_amdgcn_mfma_f32_16x16x32_f16(a2[0], *(const f16x8*)(wp), a, 0, 0, 0);
            a = __builtin_amdgcn_mfma_f32_16x16x32_f16(a2[1], *(const f16x8*)(wp + 32), a, 0, 0, 0);
            float bb = (t < 4) ? b1c[t] : 0.f;   // b-part (cols 64..127) has no bias
#pragma unroll
            for (int r = 0; r < 4; ++r)
                hwb[(kg * 4 + r) * 136 + q + 16 * t] = (_Float16)(a[r] + bb);
        }
        // coalesced copy-out: 16 nodes x 128 halves
#pragma unroll
        for (int i = lane; i < 256; i += 64) {
            int nd = i >> 4, off = (i & 15) * 8;
            int n2 = m0 + nd;
            if (n2 < NN)
                *(uint4*)(abh + (size_t)n2 * 128 + off) = *(const uint4*)&hwb[nd * 136 + off];
        }
    }
}

// ---------------- edge classifier: 8 lanes/edge, TWO edges per group (dual gather chains) ----------------
__global__ __launch_bounds__(256) void edge_kernel(const ushort* __restrict__ abh,
                                                   const int* __restrict__ esrc, const int* __restrict__ edst,
                                                   const float* __restrict__ W2, const float* __restrict__ b2,
                                                   float* __restrict__ out) {
    const int HALF = NE / 2;
    int t = blockIdx.x * 256 + threadIdx.x;
    int g = t >> 3, q = t & 7;
    if (g >= HALF) return;
    int e0 = g, e1 = g + HALF;
    int s0 = esrc[e0], d0 = edst[e0];
    int s1 = esrc[e1], d1 = edst[e1];
    // 4 independent gather chains in flight
    uint4 a40 = *(const uint4*)(abh + (size_t)s0 * 128 + q * 8);
    uint4 b40 = *(const uint4*)(abh + (size_t)d0 * 128 + 64 + q * 8);
    uint4 a41 = *(const uint4*)(abh + (size_t)s1 * 128 + q * 8);
    uint4 b41 = *(const uint4*)(abh + (size_t)d1 * 128 + 64 + q * 8);
    float4 w[4];
#pragma unroll
    for (int j = 0; j < 4; ++j) w[j] = ((const float4*)(W2 + q * 16))[j];
    float c0 = b2[0], c1 = b2[1];

    float o00 = 0.f, o01 = 0.f, o10 = 0.f, o11 = 0.f;
    const __half2* ah0 = (const __half2*)&a40;
    const __half2* bh0 = (const __half2*)&b40;
    const __half2* ah1 = (const __half2*)&a41;
    const __half2* bh1 = (const __half2*)&b41;
#pragma unroll
    for (int j = 0; j < 4; ++j) {
        float2 av = __half22float2(ah0[j]);
        float2 bv = __half22float2(bh0[j]);
        float h0 = fmaxf(av.x + bv.x, 0.f);
        float h1 = fmaxf(av.y + bv.y, 0.f);
        o00 = fmaf(h0, w[j].x, fmaf(h1, w[j].z, o00));
        o01 = fmaf(h0, w[j].y, fmaf(h1, w[j].w, o01));
        float2 av1 = __half22float2(ah1[j]);
        float2 bv1 = __half22float2(bh1[j]);
        float g0 = fmaxf(av1.x + bv1.x, 0.f);
        float g1 = fmaxf(av1.y + bv1.y, 0.f);
        o10 = fmaf(g0, w[j].x, fmaf(g1, w[j].z, o10));
        o11 = fmaf(g0, w[j].y, fmaf(g1, w[j].w, o11));
    }
#pragma unroll
    for (int m = 4; m >= 1; m >>= 1) {
        o00 += __shfl_xor(o00, m, 8);
        o01 += __shfl_xor(o01, m, 8);
        o10 += __shfl_xor(o10, m, 8);
        o11 += __shfl_xor(o11, m, 8);
    }
    if (q == 0) {
        *(float2*)(out + (size_t)e0 * 2) = make_float2(o00 + c0, o01 + c1);
        *(float2*)(out + (size_t)e1 * 2) = make_float2(o10 + c0, o11 + c1);
    }
}

extern "C" void kernel_launch(void* const* d_in, const int* in_sizes, int n_in,
                              void* d_out, int out_size, void* d_ws, size_t ws_size,
                              hipStream_t stream) {
    (void)in_sizes; (void)n_in; (void)out_size; (void)ws_size;
    const float* x    = (const float*)d_in[0];
    const int*   ei   = (const int*)d_in[1];
    const float* ew   = (const float*)d_in[2];
    const int*   esrc = (const int*)d_in[3];
    const int*   edst = (const int*)d_in[4];
    const float* Wz   = (const float*)d_in[6];
    const float* bz   = (const float*)d_in[7];
    const float* lzW  = (const float*)d_in[8];
    const float* lzb  = (const float*)d_in[9];
    const float* Wh   = (const float*)d_in[14];
    const float* bh   = (const float*)d_in[15];
    const float* lhW  = (const float*)d_in[16];
    const float* lhb  = (const float*)d_in[17];
    const float* W1   = (const float*)d_in[18];
    const float* b1   = (const float*)d_in[19];
    const float* W2   = (const float*)d_in[20];
    const float* b2   = (const float*)d_in[21];
    float* out = (float*)d_out;

    float* ws = (float*)d_ws;
    float* bzp = ws;                                     // 64
    float* bhp = ws + 64;                                // 64
    _Float16* Wct = (_Float16*)(ws + 128);               // 12288 halves
    _Float16* W1t = (_Float16*)(ws + 6272);              // 8192 halves
    unsigned* degcnt = (unsigned*)(ws + 10368);          // 100K nodes x 16 u32 (64B line each) = 6.4MB
    float* dinv     = ws + 1610368;                      // 100K f32
    int*   cnt      = (int*)(ws + 1710368);              // 100K i32
    int*   rowstart = (int*)(ws + 1810368);              // 100K i32
    int*   bsums    = (int*)(ws + 1910368);              // 512
    ushort* yh   = (ushort*)(ws + 1910880);              // 9.6M halves (100K x 96), 16B aligned
    ushort* aggh = (ushort*)(ws + 6710880);              // 8M halves (100K x 80), 16B aligned
    unsigned char* rank = (unsigned char*)(ws + 10710880); // 1.6M u8 (live: deg_scatter..csr_fill)
    unsigned* csr  = (unsigned*)(ws + 11110880);         // 1.6M u32 dense CSR (live: csr_fill..gather)
    ushort* abh = (ushort*)(ws + 10710880);              // 12.8M halves (live: node..edge), aliases rank+csr

    const int* g_src = ei;
    const int* g_dst = ei + NE;

    fuse_weights<<<dim3(128, 2), 128, 0, stream>>>(Wz, bz, lzW, lzb, Wh, bh, lhW, lhb,
                                                   W1, Wct, W1t, bzp, bhp);
    hipMemsetAsync(degcnt, 0, (size_t)NN * 16 * sizeof(unsigned), stream);
    deg_scatter<<<(NE + 255) / 256, 256, 0, stream>>>(g_dst, ew, degcnt, rank);
    build_y<<<(NN * 48 + 255) / 256, 256, 0, stream>>>(x, degcnt, yh, dinv, cnt);
    scan1<<<NBLK, 256, 0, stream>>>(cnt, rowstart, bsums);
    scan2<<<1, 512, 0, stream>>>(bsums);
    scan3<<<NBLK, 256, 0, stream>>>(rowstart, bsums);
    csr_fill<<<(NE + 255) / 256, 256, 0, stream>>>(g_src, g_dst, ew, rowstart, rank, csr);
    gather_agg<<<(NN * 8 + 255) / 256, 256, 0, stream>>>(rowstart, cnt, csr, dinv, yh, aggh);
    node_kernel<<<512, 256, 0, stream>>>(aggh, Wct, W1t, bzp, bhp, b1, abh);
    edge_kernel<<<(NE / 2 * 8 + 255) / 256, 256, 0, stream>>>(abh, esrc, edst, W2, b2, out);
}

// Round 12
// 191.897 us; speedup vs baseline: 1.5012x; 1.2868x over previous
//
#include <hip/hip_runtime.h>
#include <hip/hip_bf16.h>
#include <hip/hip_fp16.h>

#define NN 100000
#define NE 1600000
#define FI 80
#define HD 64
#define NBUK 196   // ceil(NN/512) buckets of 512 nodes
#define BSH 9      // 512 nodes per bucket
#define NBLKA 391  // partition blocks; NBLKA*EPB >= NE
#define EPB 4096   // edges per partition block

typedef _Float16 f16x8 __attribute__((ext_vector_type(8)));
typedef float f32x4 __attribute__((ext_vector_type(4)));

// ---------------- fused weight precompute ----------------
// Wc_t[j][k] (fp16, [128][96], k>=80 zero): j<64: (Wz@lzW[0:64])[k][j]; j>=64: (Wh@lhW[0:64])[k][j-64]
// W1_t[j][k] (fp16, [128][64]): j<64: W1[k][j]; j>=64: W1[64+k][j-64]  (mlp_W1 is (128,64), stride 64)
// bzp/bhp = fused gate biases (f32).  (H=0 => R-gate dead; softmax(1)=1 => attention dead)
__global__ void fuse_weights(const float* __restrict__ Wz, const float* __restrict__ bz,
                             const float* __restrict__ lzW, const float* __restrict__ lzb,
                             const float* __restrict__ Wh, const float* __restrict__ bh,
                             const float* __restrict__ lhW, const float* __restrict__ lhb,
                             const float* __restrict__ W1,
                             _Float16* __restrict__ Wct, _Float16* __restrict__ W1t,
                             float* __restrict__ bzp, float* __restrict__ bhp) {
    int j = blockIdx.x;      // 0..127 output col
    int k = threadIdx.x;     // 0..127
    if (blockIdx.y == 1) {
        if (k < HD) {
            float v = (j < HD) ? W1[k * HD + j] : W1[(HD + k) * HD + (j - HD)];
            W1t[j * HD + k] = (_Float16)v;
        }
        return;
    }
    bool isZ = j < 64;
    int jj = isZ ? j : j - 64;
    const float* W = isZ ? Wz : Wh;
    const float* L = isZ ? lzW : lhW;
    if (k < FI) {
        float acc = 0.f;
        for (int i = 0; i < HD; ++i) acc = fmaf(W[k * HD + i], L[i * HD + jj], acc);
        Wct[j * 96 + k] = (_Float16)acc;
    } else if (k < 96) {
        Wct[j * 96 + k] = (_Float16)0.f;
    } else if (k == 96) {
        const float* bb = isZ ? bz : bh;
        const float* lb = isZ ? lzb : lhb;
        float acc = lb[jj];
        for (int i = 0; i < HD; ++i) acc = fmaf(bb[i], L[i * HD + jj], acc);
        (isZ ? bzp : bhp)[jj] = acc;
    }
}

// ---------------- radix-partition CSR build: ZERO global atomics ----------------
// (R11 diag: random returning atomics cap at ~25 Gops/s device-wide regardless of layout;
//  1.6M atomics = 64us floor. Replace with histogram + scan + partition, LDS atomics only.)

// K1: per-block bucket histogram
__global__ __launch_bounds__(256) void bucket_count(const int* __restrict__ gdst,
                                                    unsigned* __restrict__ blockcounts) {
    __shared__ unsigned lcnt[NBUK];
    for (int i = threadIdx.x; i < NBUK; i += 256) lcnt[i] = 0;
    __syncthreads();
    int base = blockIdx.x * EPB;
#pragma unroll
    for (int i = 0; i < EPB / 256; ++i) {
        int e = base + i * 256 + threadIdx.x;
        if (e < NE) atomicAdd(&lcnt[(unsigned)gdst[e] >> BSH], 1u);
    }
    __syncthreads();
    for (int i = threadIdx.x; i < NBUK; i += 256)
        blockcounts[i * NBLKA + blockIdx.x] = lcnt[i];   // bucket-major
}

// K2a: per-bucket exclusive scan over blocks; emit bucket totals
__global__ __launch_bounds__(512) void bucket_scan_a(unsigned* __restrict__ blockcounts,
                                                     unsigned* __restrict__ buktot) {
    __shared__ unsigned s[512];
    int b = blockIdx.x, t = threadIdx.x;
    unsigned v = (t < NBLKA) ? blockcounts[b * NBLKA + t] : 0;
    s[t] = v;
    __syncthreads();
    for (int off = 1; off < 512; off <<= 1) {
        unsigned x = 0;
        if (t >= off) x = s[t - off];
        __syncthreads();
        s[t] += x;
        __syncthreads();
    }
    if (t < NBLKA) blockcounts[b * NBLKA + t] = s[t] - v;   // exclusive within bucket
    if (t == 511) buktot[b] = s[511];
}

// K2b: exclusive scan of bucket totals -> bukstart[0..NBUK]
__global__ void bucket_scan_b(const unsigned* __restrict__ buktot, unsigned* __restrict__ bukstart) {
    __shared__ unsigned s[256];
    int t = threadIdx.x;
    unsigned v = (t < NBUK) ? buktot[t] : 0;
    s[t] = v;
    __syncthreads();
    for (int off = 1; off < 256; off <<= 1) {
        unsigned x = 0;
        if (t >= off) x = s[t - off];
        __syncthreads();
        s[t] += x;
        __syncthreads();
    }
    if (t < NBUK) bukstart[t] = s[t] - v;
    if (t == NBUK - 1) bukstart[NBUK] = s[t];   // == NE
}

// K3: partition edges into bucket segments. payload: dl[9] | src[17] | ew_q20[20]
__global__ __launch_bounds__(256) void bucket_scatter(const int* __restrict__ gsrc,
                                                      const int* __restrict__ gdst,
                                                      const float* __restrict__ ew,
                                                      const unsigned* __restrict__ blockcounts,
                                                      const unsigned* __restrict__ bukstart,
                                                      unsigned long long* __restrict__ bedges) {
    __shared__ unsigned cur[NBUK];
    for (int i = threadIdx.x; i < NBUK; i += 256)
        cur[i] = bukstart[i] + blockcounts[i * NBLKA + blockIdx.x];
    __syncthreads();
    int base = blockIdx.x * EPB;
#pragma unroll
    for (int i = 0; i < EPB / 256; ++i) {
        int e = base + i * 256 + threadIdx.x;
        if (e < NE) {
            unsigned d = (unsigned)gdst[e];
            unsigned b = d >> BSH;
            unsigned pos = atomicAdd(&cur[b], 1u);                    // LDS atomic
            unsigned q20 = (unsigned)(ew[e] * 1048575.0f);            // floor, <= 1048574 (no src-field bleed)
            unsigned long long pay = ((unsigned long long)(d & 511u) << 37) |
                                     ((unsigned long long)(unsigned)gsrc[e] << 20) |
                                     (unsigned long long)q20;
            bedges[pos] = pay;
        }
    }
}

// K4: per-bucket CSR build: LDS histogram+degsum -> LDS scan -> LDS-cursor scatter
__global__ __launch_bounds__(512) void csr_build(const unsigned long long* __restrict__ bedges,
                                                 const unsigned* __restrict__ bukstart,
                                                 unsigned* __restrict__ csr,
                                                 float* __restrict__ dinv,
                                                 int* __restrict__ cnt,
                                                 int* __restrict__ rowstart) {
    __shared__ unsigned lcnt[512];
    __shared__ unsigned ldeg[512];   // q20 fixed-point degree sum (max ~60*2^20 << 2^32)
    __shared__ unsigned lrow[512];
    int b = blockIdx.x, t = threadIdx.x;
    lcnt[t] = 0;
    ldeg[t] = 0;
    __syncthreads();
    unsigned beg = bukstart[b], end = bukstart[b + 1];
    for (unsigned i = beg + t; i < end; i += 512) {
        unsigned long long p = bedges[i];
        unsigned dl = (unsigned)(p >> 37);
        atomicAdd(&lcnt[dl], 1u);
        atomicAdd(&ldeg[dl], (unsigned)(p & 0xFFFFFu));
    }
    __syncthreads();
    unsigned v = lcnt[t];
    lrow[t] = v;
    __syncthreads();
    for (int off = 1; off < 512; off <<= 1) {
        unsigned x = 0;
        if (t >= off) x = lrow[t - off];
        __syncthreads();
        lrow[t] += x;
        __syncthreads();
    }
    unsigned myrow = lrow[t] - v;   // exclusive, bucket-relative
    __syncthreads();
    lrow[t] = beg + myrow;          // global cursor
    __syncthreads();
    for (unsigned i = beg + t; i < end; i += 512) {
        unsigned long long p = bedges[i];
        unsigned dl = (unsigned)(p >> 37);
        unsigned src = (unsigned)((p >> 20) & 0x1FFFFu);
        unsigned q15 = ((unsigned)(p & 0xFFFFFu)) >> 5;    // <= 32767
        unsigned pos = atomicAdd(&lrow[dl], 1u);           // LDS atomic
        csr[pos] = (src << 15) | q15;
    }
    int node = (b << BSH) + t;
    if (node < NN) {
        float deg = 1.0f + (float)ldeg[t] * (1.0f / 1048576.0f);
        dinv[node] = rsqrtf(deg);
        cnt[node] = (int)lcnt[t];
        rowstart[node] = (int)(beg + myrow);
    }
}

// ---------------- y table: y[n] = dinv[n]*x[n], fp16, rows padded to 96 halves ----------------
__global__ void build_y(const float* __restrict__ x, const float* __restrict__ dinv,
                        ushort* __restrict__ yh) {
    int i = blockIdx.x * 256 + threadIdx.x;   // over NN*48 half2
    if (i >= NN * 48) return;
    int n = i / 48, p = i % 48;
    float di = dinv[n];
    __half2 h;
    if (p < 40) {
        float2 vv = *(const float2*)(x + (size_t)n * FI + 2 * p);
        h = __floats2half2_rn(di * vv.x, di * vv.y);
    } else {
        h = __floats2half2_rn(0.f, 0.f);
    }
    *(__half2*)(yh + (size_t)n * 96 + 2 * p) = h;
}

// ---------------- gather aggregation (csr entry prefetched 1 ahead) ----------------
// acc = y[n] + sum ew*y[src];  agg[n] = dinv[n]*acc  (fp16 out)
__global__ __launch_bounds__(256) void gather_agg(const int* __restrict__ rowstart,
                                                  const int* __restrict__ cnt,
                                                  const unsigned* __restrict__ csr,
                                                  const float* __restrict__ dinv,
                                                  const ushort* __restrict__ yh,
                                                  ushort* __restrict__ aggh) {
    int t = blockIdx.x * 256 + threadIdx.x;
    int n = t >> 3, k = t & 7;
    if (n >= NN) return;
    float di = dinv[n];
    const ushort* yn = yh + (size_t)n * 96;
    float2 acc[5];
#pragma unroll
    for (int j = 0; j < 5; ++j)
        acc[j] = __half22float2(*(const __half2*)(yn + 2 * k + 16 * j));
    int beg = rowstart[n], end = beg + cnt[n];
    unsigned ent = (beg < end) ? csr[beg] : 0u;
    for (int i = beg; i < end; ++i) {
        unsigned cur = ent;
        if (i + 1 < end) ent = csr[i + 1];
        float c = (float)(cur & 0x7FFFu) * (1.0f / 32767.0f);
        const ushort* ys = yh + (size_t)(cur >> 15) * 96;
#pragma unroll
        for (int j = 0; j < 5; ++j) {
            float2 v = __half22float2(*(const __half2*)(ys + 2 * k + 16 * j));
            acc[j].x = fmaf(c, v.x, acc[j].x);
            acc[j].y = fmaf(c, v.y, acc[j].y);
        }
    }
    ushort* an = aggh + (size_t)n * FI;
#pragma unroll
    for (int j = 0; j < 5; ++j)
        *(__half2*)(an + 2 * k + 16 * j) = __floats2half2_rn(di * acc[j].x, di * acc[j].y);
}

// ---------------- node kernel: MFMA fp16 two-stage GEMM ----------------
// GEMM1: u(16x80,fp16) @ Wc(80x128) -> gates -> h(16x64);  GEMM2: h @ W1(64x128) -> ab fp16
// C-layout: col=lane&15, row=(lane>>4)*4+r (m89-verified); k-perm consistent on A/B sides.
__global__ __launch_bounds__(256) void node_kernel(const ushort* __restrict__ aggh,
        const _Float16* __restrict__ Wct, const _Float16* __restrict__ W1t,
        const float* __restrict__ bzp, const float* __restrict__ bhp,
        const float* __restrict__ b1, ushort* __restrict__ abh) {
    __shared__ __align__(16) _Float16 sWc[128 * 104];
    __shared__ __align__(16) _Float16 sW1[128 * 72];
    __shared__ __align__(16) _Float16 wbuf[4][2176];
    int tid = threadIdx.x;
    for (int i = tid; i < 1536; i += 256) {
        int col = i / 12, ko = (i % 12) * 8;
        *(uint4*)&sWc[col * 104 + ko] = ((const uint4*)Wct)[i];
    }
    for (int i = tid; i < 1024; i += 256) {
        int col = i / 8, ko = (i % 8) * 8;
        *(uint4*)&sW1[col * 72 + ko] = ((const uint4*)W1t)[i];
    }
    __syncthreads();

    int lane = tid & 63, wv = tid >> 6;
    int q = lane & 15, kg = lane >> 4;
    _Float16* hwb = wbuf[wv];

    float bzc[4], bhc[4], b1c[4];
#pragma unroll
    for (int t = 0; t < 4; ++t) {
        bzc[t] = bzp[q + 16 * t];
        bhc[t] = bhp[q + 16 * t];
        b1c[t] = b1[q + 16 * t];
    }

    const int NT = (NN + 63) >> 6;
    for (int tile = blockIdx.x; tile < NT; tile += gridDim.x) {
        int m0 = tile * 64 + wv * 16;
        int node = m0 + q;
        bool rv = node < NN;
        const _Float16* up = (const _Float16*)(aggh + (size_t)node * FI);
        f16x8 a1[3];
#pragma unroll
        for (int ks = 0; ks < 3; ++ks) {
            int kk = ks * 32 + kg * 8;
            a1[ks] = (rv && kk < FI) ? *(const f16x8*)(up + kk) : f16x8{};
        }
        f32x4 acc[8];
#pragma unroll
        for (int t = 0; t < 8; ++t) {
            const _Float16* wp = &sWc[(q + 16 * t) * 104 + kg * 8];
            f32x4 a = {0.f, 0.f, 0.f, 0.f};
            a = __builtin_amdgcn_mfma_f32_16x16x32_f16(a1[0], *(const f16x8*)(wp), a, 0, 0, 0);
            a = __builtin_amdgcn_mfma_f32_16x16x32_f16(a1[1], *(const f16x8*)(wp + 32), a, 0, 0, 0);
            a = __builtin_amdgcn_mfma_f32_16x16x32_f16(a1[2], *(const f16x8*)(wp + 64), a, 0, 0, 0);
            acc[t] = a;
        }
#pragma unroll
        for (int t = 0; t < 4; ++t) {
#pragma unroll
            for (int r = 0; r < 4; ++r) {
                float z = acc[t][r] + bzc[t];
                float p = acc[t + 4][r] + bhc[t];
                float Z = 1.f / (1.f + __expf(-z));
                float p2 = fminf(fmaxf(2.f * p, -60.f), 60.f);
                float e2 = __expf(p2);
                float Ht = (e2 - 1.f) / (e2 + 1.f);
                hwb[(kg * 4 + r) * 72 + q + 16 * t] = (_Float16)((1.f - Z) * Ht);
            }
        }
        f16x8 a2[2];
        a2[0] = *(const f16x8*)&hwb[q * 72 + kg * 8];
        a2[1] = *(const f16x8*)&hwb[q * 72 + 32 + kg * 8];
#pragma unroll
        for (int t = 0; t < 8; ++t) {
            const _Float16* wp = &sW1[(q + 16 * t) * 72 + kg * 8];
            f32x4 a = {0.f, 0.f, 0.f, 0.f};
            a = __builtin_amdgcn_mfma_f32_16x16x32_f16(a2[0], *(const f16x8*)(wp), a, 0, 0, 0);
            a = __builtin_amdgcn_mfma_f32_16x16x32_f16(a2[1], *(const f16x8*)(wp + 32), a, 0, 0, 0);
            float bb = (t < 4) ? b1c[t] : 0.f;
#pragma unroll
            for (int r = 0; r < 4; ++r)
                hwb[(kg * 4 + r) * 136 + q + 16 * t] = (_Float16)(a[r] + bb);
        }
#pragma unroll
        for (int i = lane; i < 256; i += 64) {
            int nd = i >> 4, off = (i & 15) * 8;
            int n2 = m0 + nd;
            if (n2 < NN)
                *(uint4*)(abh + (size_t)n2 * 128 + off) = *(const uint4*)&hwb[nd * 136 + off];
        }
    }
}

// ---------------- edge classifier: 8 lanes/edge, TWO edges per group (dual gather chains) ----------------
__global__ __launch_bounds__(256) void edge_kernel(const ushort* __restrict__ abh,
                                                   const int* __restrict__ esrc, const int* __restrict__ edst,
                                                   const float* __restrict__ W2, const float* __restrict__ b2,
                                                   float* __restrict__ out) {
    const int HALF = NE / 2;
    int t = blockIdx.x * 256 + threadIdx.x;
    int g = t >> 3, q = t & 7;
    if (g >= HALF) return;
    int e0 = g, e1 = g + HALF;
    int s0 = esrc[e0], d0 = edst[e0];
    int s1 = esrc[e1], d1 = edst[e1];
    uint4 a40 = *(const uint4*)(abh + (size_t)s0 * 128 + q * 8);
    uint4 b40 = *(const uint4*)(abh + (size_t)d0 * 128 + 64 + q * 8);
    uint4 a41 = *(const uint4*)(abh + (size_t)s1 * 128 + q * 8);
    uint4 b41 = *(const uint4*)(abh + (size_t)d1 * 128 + 64 + q * 8);
    float4 w[4];
#pragma unroll
    for (int j = 0; j < 4; ++j) w[j] = ((const float4*)(W2 + q * 16))[j];
    float c0 = b2[0], c1 = b2[1];

    float o00 = 0.f, o01 = 0.f, o10 = 0.f, o11 = 0.f;
    const __half2* ah0 = (const __half2*)&a40;
    const __half2* bh0 = (const __half2*)&b40;
    const __half2* ah1 = (const __half2*)&a41;
    const __half2* bh1 = (const __half2*)&b41;
#pragma unroll
    for (int j = 0; j < 4; ++j) {
        float2 av = __half22float2(ah0[j]);
        float2 bv = __half22float2(bh0[j]);
        float h0 = fmaxf(av.x + bv.x, 0.f);
        float h1 = fmaxf(av.y + bv.y, 0.f);
        o00 = fmaf(h0, w[j].x, fmaf(h1, w[j].z, o00));
        o01 = fmaf(h0, w[j].y, fmaf(h1, w[j].w, o01));
        float2 av1 = __half22float2(ah1[j]);
        float2 bv1 = __half22float2(bh1[j]);
        float g0 = fmaxf(av1.x + bv1.x, 0.f);
        float g1 = fmaxf(av1.y + bv1.y, 0.f);
        o10 = fmaf(g0, w[j].x, fmaf(g1, w[j].z, o10));
        o11 = fmaf(g0, w[j].y, fmaf(g1, w[j].w, o11));
    }
#pragma unroll
    for (int m = 4; m >= 1; m >>= 1) {
        o00 += __shfl_xor(o00, m, 8);
        o01 += __shfl_xor(o01, m, 8);
        o10 += __shfl_xor(o10, m, 8);
        o11 += __shfl_xor(o11, m, 8);
    }
    if (q == 0) {
        *(float2*)(out + (size_t)e0 * 2) = make_float2(o00 + c0, o01 + c1);
        *(float2*)(out + (size_t)e1 * 2) = make_float2(o10 + c0, o11 + c1);
    }
}

extern "C" void kernel_launch(void* const* d_in, const int* in_sizes, int n_in,
                              void* d_out, int out_size, void* d_ws, size_t ws_size,
                              hipStream_t stream) {
    (void)in_sizes; (void)n_in; (void)out_size; (void)ws_size;
    const float* x    = (const float*)d_in[0];
    const int*   ei   = (const int*)d_in[1];
    const float* ew   = (const float*)d_in[2];
    const int*   esrc = (const int*)d_in[3];
    const int*   edst = (const int*)d_in[4];
    const float* Wz   = (const float*)d_in[6];
    const float* bz   = (const float*)d_in[7];
    const float* lzW  = (const float*)d_in[8];
    const float* lzb  = (const float*)d_in[9];
    const float* Wh   = (const float*)d_in[14];
    const float* bh   = (const float*)d_in[15];
    const float* lhW  = (const float*)d_in[16];
    const float* lhb  = (const float*)d_in[17];
    const float* W1   = (const float*)d_in[18];
    const float* b1   = (const float*)d_in[19];
    const float* W2   = (const float*)d_in[20];
    const float* b2   = (const float*)d_in[21];
    float* out = (float*)d_out;

    float* ws = (float*)d_ws;
    float* bzp = ws;                                       // 64
    float* bhp = ws + 64;                                  // 64
    _Float16* Wct = (_Float16*)(ws + 128);                 // 12288 halves
    _Float16* W1t = (_Float16*)(ws + 6272);                // 8192 halves
    float*    dinv     = ws + 10368;                       // 100K
    int*      cnt      = (int*)(ws + 110368);              // 100K
    int*      rowstart = (int*)(ws + 210368);              // 100K
    unsigned* blockcounts = (unsigned*)(ws + 310368);      // 196*391 = 76,636 u32
    unsigned* buktot   = (unsigned*)(ws + 387008);         // 196
    unsigned* bukstart = (unsigned*)(ws + 387408);         // 197
    ushort*   yh   = (ushort*)(ws + 387808);               // 9.6M halves, 16B aligned
    ushort*   aggh = (ushort*)(ws + 5187808);              // 8M halves
    // region R: bedges (live K3..K4) + csr (live K4..gather); abh (live node..edge) aliases both
    unsigned long long* bedges = (unsigned long long*)(ws + 9187808);  // 1.6M u64, 8B aligned
    unsigned* csr = (unsigned*)(ws + 12387808);            // 1.6M u32
    ushort*   abh = (ushort*)(ws + 9187808);               // 12.8M halves

    const int* g_src = ei;
    const int* g_dst = ei + NE;

    fuse_weights<<<dim3(128, 2), 128, 0, stream>>>(Wz, bz, lzW, lzb, Wh, bh, lhW, lhb,
                                                   W1, Wct, W1t, bzp, bhp);
    bucket_count<<<NBLKA, 256, 0, stream>>>(g_dst, blockcounts);
    bucket_scan_a<<<NBUK, 512, 0, stream>>>(blockcounts, buktot);
    bucket_scan_b<<<1, 256, 0, stream>>>(buktot, bukstart);
    bucket_scatter<<<NBLKA, 256, 0, stream>>>(g_src, g_dst, ew, blockcounts, bukstart, bedges);
    csr_build<<<NBUK, 512, 0, stream>>>(bedges, bukstart, csr, dinv, cnt, rowstart);
    build_y<<<(NN * 48 + 255) / 256, 256, 0, stream>>>(x, dinv, yh);
    gather_agg<<<(NN * 8 + 255) / 256, 256, 0, stream>>>(rowstart, cnt, csr, dinv, yh, aggh);
    node_kernel<<<512, 256, 0, stream>>>(aggh, Wct, W1t, bzp, bhp, b1, abh);
    edge_kernel<<<(NE / 2 * 8 + 255) / 256, 256, 0, stream>>>(abh, esrc, edst, W2, b2, out);
}